// Round 1
// baseline (381.240 us; speedup 1.0000x reference)
//
#include <hip/hip_runtime.h>
#include <hip/hip_bf16.h>
#include <math.h>

#define N_NODES 100000
#define F_IN    128
#define HC      128      // H*C
#define NH      4
#define SLOPE   0.2f

#define PADK    136      // LDS row stride in shorts (128 + 8 pad)
#define NSB     98       // scan blocks = ceil(N/1024)

typedef __attribute__((ext_vector_type(8))) short short8;   // bf16x8 MFMA frag
typedef __attribute__((ext_vector_type(4))) float f32x4;    // MFMA accum
typedef __attribute__((ext_vector_type(2))) float fx2;      // native float2 (NT store ok)

static __device__ __forceinline__ float leaky(float x) { return x > 0.f ? x : SLOPE * x; }

static __device__ __forceinline__ short f2bs(float f) {
    __hip_bfloat16 b = __float2bfloat16(f);   // RTN-even
    return *reinterpret_cast<short*>(&b);
}

// ---------------------------------------------------------------------------
// K0: one-time W conversion: W[k][n] fp32 -> wt[n][k] bf16 (n-major, k inner)
// so k_gemm stages W with pure 16B copies (no per-block f2bs, no strided
// ds_write_b16 bank conflicts).
// ---------------------------------------------------------------------------
__global__ __launch_bounds__(256) void k_prep(const float* __restrict__ W,
                                              unsigned short* __restrict__ wt)
{
    int t = blockIdx.x * 256 + threadIdx.x;
    if (t < 128 * 128) {
        int k = t >> 7, n = t & 127;
        wt[n * 128 + k] = (unsigned short)f2bs(W[k * HC + n]);
    }
}

// ---------------------------------------------------------------------------
// K1: h = x @ W via bf16 MFMA (fp32 accum). Block = 64 rows x 128 cols,
// 4 waves; wave w owns rows w*16..w*16+15; 8 n-tiles x 4 k-blocks of
// mfma_f32_16x16x32_bf16. x converted to bf16 during LDS staging; W staged
// from preconverted bf16 wt (coalesced 16B copies).
// Epilogue: bf16 h store + fp32 a_src/a_dst (per-head dot + 4-step shfl tree).
// ---------------------------------------------------------------------------
__global__ __launch_bounds__(256) void k_gemm(const float* __restrict__ x,
                                              const unsigned short* __restrict__ wt,
                                              const float* __restrict__ att_src,
                                              const float* __restrict__ att_dst,
                                              unsigned short* __restrict__ hb,
                                              float* __restrict__ a_src,
                                              float* __restrict__ a_dst)
{
    __shared__ short xs[64 * PADK];    // bf16 x tile [row][k]   17.4 KB
    __shared__ short ws[128 * PADK];   // bf16 W^T    [n][k]     34.8 KB
    const int t  = threadIdx.x;
    const int r0 = blockIdx.x * 64;

    // stage x tile (fp32 -> bf16): 64 rows x 32 float4 chunks
    for (int i = t; i < 2048; i += 256) {
        int row = i >> 5, kq = (i & 31) * 4;
        int gr = r0 + row;
        float4 v = make_float4(0.f, 0.f, 0.f, 0.f);
        if (gr < N_NODES) v = ((const float4*)(x + (size_t)gr * F_IN))[i & 31];
        short* p = &xs[row * PADK + kq];
        p[0] = f2bs(v.x); p[1] = f2bs(v.y); p[2] = f2bs(v.z); p[3] = f2bs(v.w);
    }
    // stage W^T (bf16 copy): thread i copies 16B; global reads fully contiguous
    for (int i = t; i < 2048; i += 256) {
        int n = i >> 4, k0 = (i & 15) * 8;
        *(float4*)&ws[n * PADK + k0] = *(const float4*)&wt[n * 128 + k0];
    }
    __syncthreads();

    const int wave = t >> 6, lane = t & 63;
    const int quad = lane >> 4, l16 = lane & 15;
    const int wrow = wave * 16;

    f32x4 acc[8];
    #pragma unroll
    for (int nt = 0; nt < 8; ++nt) acc[nt] = (f32x4){0.f, 0.f, 0.f, 0.f};

    const short* ap = &xs[(wrow + l16) * PADK + quad * 8];
    #pragma unroll
    for (int kb = 0; kb < 4; ++kb) {
        short8 a = *(const short8*)(ap + kb * 32);
        #pragma unroll
        for (int nt = 0; nt < 8; ++nt) {
            short8 b = *(const short8*)&ws[(nt * 16 + l16) * PADK + kb * 32 + quad * 8];
            acc[nt] = __builtin_amdgcn_mfma_f32_16x16x32_bf16(a, b, acc[nt], 0, 0, 0);
        }
    }

    // att vectors for my column residue: col = nt*16 + l16
    float att_s[8], att_d[8];
    #pragma unroll
    for (int nt = 0; nt < 8; ++nt) {
        att_s[nt] = att_src[nt * 16 + l16];
        att_d[nt] = att_dst[nt * 16 + l16];
    }

    #pragma unroll
    for (int g = 0; g < 4; ++g) {
        int r = r0 + wrow + quad * 4 + g;
        // h store: D[row][col=nt*16+l16]
        if (r < N_NODES) {
            #pragma unroll
            for (int nt = 0; nt < 8; ++nt)
                hb[(size_t)r * HC + nt * 16 + l16] = (unsigned short)f2bs(acc[nt][g]);
        }
        // per-head partials (head = nt>>1)
        float s0 = acc[0][g] * att_s[0] + acc[1][g] * att_s[1];
        float s1 = acc[2][g] * att_s[2] + acc[3][g] * att_s[3];
        float s2 = acc[4][g] * att_s[4] + acc[5][g] * att_s[5];
        float s3 = acc[6][g] * att_s[6] + acc[7][g] * att_s[7];
        float d0 = acc[0][g] * att_d[0] + acc[1][g] * att_d[1];
        float d1 = acc[2][g] * att_d[2] + acc[3][g] * att_d[3];
        float d2 = acc[4][g] * att_d[4] + acc[5][g] * att_d[5];
        float d3 = acc[6][g] * att_d[6] + acc[7][g] * att_d[7];
        #pragma unroll
        for (int o = 1; o < 16; o <<= 1) {
            s0 += __shfl_xor(s0, o); s1 += __shfl_xor(s1, o);
            s2 += __shfl_xor(s2, o); s3 += __shfl_xor(s3, o);
            d0 += __shfl_xor(d0, o); d1 += __shfl_xor(d1, o);
            d2 += __shfl_xor(d2, o); d3 += __shfl_xor(d3, o);
        }
        if (l16 == 0 && r < N_NODES) {
            *(float4*)&a_src[r * NH] = make_float4(s0, s1, s2, s3);
            *(float4*)&a_dst[r * NH] = make_float4(d0, d1, d2, d3);
        }
    }
}

// ---------------------------------------------------------------------------
// K2: per-node in-degree via global atomics (deg pre-zeroed by memset).
// ---------------------------------------------------------------------------
__global__ __launch_bounds__(256) void k_deg(const int* __restrict__ dstp,
                                             int* __restrict__ deg, int E)
{
    int i = blockIdx.x * 2048 + threadIdx.x;
    #pragma unroll
    for (int j = 0; j < 8; ++j, i += 256)
        if (i < E) atomicAdd(&deg[dstp[i]], 1);
}

// ---------------------------------------------------------------------------
// K3a/b/c: hierarchical exclusive scan of (deg[n]+1) -> rowse/cursor/col[self]
// ---------------------------------------------------------------------------
__global__ __launch_bounds__(1024) void k_scanA(const int* __restrict__ deg,
                                                int* __restrict__ dx,
                                                int* __restrict__ btot)
{
    __shared__ int sdata[1024];
    const int t = threadIdx.x, b = blockIdx.x;
    const int n = b * 1024 + t;
    int v = (n < N_NODES) ? (deg[n] + 1) : 0;   // +1 = self-loop
    sdata[t] = v;
    __syncthreads();
    for (int o = 1; o < 1024; o <<= 1) {
        int add = (t >= o) ? sdata[t - o] : 0;
        __syncthreads();
        sdata[t] += add;
        __syncthreads();
    }
    if (n < N_NODES) dx[n] = sdata[t] - v;
    if (t == 1023) btot[b] = sdata[1023];
}

__global__ void k_scanB(const int* __restrict__ btot, int* __restrict__ bofs)
{
    __shared__ int sdata[128];
    const int t = threadIdx.x;
    int v = (t < NSB) ? btot[t] : 0;
    sdata[t] = v;
    __syncthreads();
    for (int o = 1; o < 128; o <<= 1) {
        int add = (t >= o) ? sdata[t - o] : 0;
        __syncthreads();
        sdata[t] += add;
        __syncthreads();
    }
    if (t < NSB) bofs[t] = sdata[t] - v;
}

__global__ __launch_bounds__(1024) void k_scanC(const int* __restrict__ deg,
                                                const int* __restrict__ dx,
                                                const int* __restrict__ bofs,
                                                int2* __restrict__ rowse,
                                                int* __restrict__ col,
                                                int* __restrict__ cursor)
{
    const int t = threadIdx.x, b = blockIdx.x;
    const int n = b * 1024 + t;
    if (n < N_NODES) {
        int start = bofs[b] + dx[n];
        int d = deg[n];
        rowse[n] = make_int2(start, start + d + 1);
        col[start] = n;           // self-loop at slot 0
        cursor[n] = start + 1;
    }
}

// ---------------------------------------------------------------------------
// K4: edge scatter into CSR via per-node atomic cursor.
// ---------------------------------------------------------------------------
__global__ __launch_bounds__(256) void k_scatter(const int* __restrict__ srcp,
                                                 const int* __restrict__ dstp,
                                                 int* __restrict__ cursor,
                                                 int* __restrict__ col, int E)
{
    int i = blockIdx.x * 2048 + threadIdx.x;
    #pragma unroll
    for (int j = 0; j < 8; ++j, i += 256) {
        if (i < E) {
            int s = srcp[i], d = dstp[i];
            int r = atomicAdd(&cursor[d], 1);
            col[r] = s;
        }
    }
}

// ---------------------------------------------------------------------------
// K5: per-dst-node softmax + aggregation. One wave per node; bf16 h gathers,
// x8 unroll; non-temporal out stores (keep L2/L3 for the hb gather set).
// (unchanged this round — isolates the CSR-build rewrite)
// ---------------------------------------------------------------------------
__global__ __launch_bounds__(256) void k_node(const unsigned short* __restrict__ hb,
                                              const float* __restrict__ a_src,
                                              const float* __restrict__ a_dst,
                                              const int2* __restrict__ rowse,
                                              const int* __restrict__ col,
                                              const float* __restrict__ bias,
                                              float* __restrict__ out)
{
    const int lane = threadIdx.x & 63;
    const int node = blockIdx.x * 4 + (threadIdx.x >> 6);
    if (node >= N_NODES) return;

    const int2 se = rowse[node];
    const int r0 = se.x, r1 = se.y;
    const int myh = lane >> 4;
    const float adm = a_dst[node * NH + myh];

    float denom = 0.f, acc0 = 0.f, acc1 = 0.f;
    int i = r0;
    for (; i + 8 <= r1; i += 8) {
        int s[8];
        #pragma unroll
        for (int j = 0; j < 8; ++j) s[j] = col[i + j];
        float as[8];
        #pragma unroll
        for (int j = 0; j < 8; ++j) as[j] = a_src[s[j] * NH + myh];
        unsigned int hv[8];
        #pragma unroll
        for (int j = 0; j < 8; ++j)
            hv[j] = *(const unsigned int*)&hb[(size_t)s[j] * HC + 2 * lane];
        #pragma unroll
        for (int j = 0; j < 8; ++j) {
            float p = __expf(leaky(as[j] + adm));
            denom += p;
            acc0 += p * __uint_as_float(hv[j] << 16);
            acc1 += p * __uint_as_float(hv[j] & 0xffff0000u);
        }
    }
    for (; i < r1; ++i) {
        int s = col[i];
        float p = __expf(leaky(a_src[s * NH + myh] + adm));
        unsigned int v = *(const unsigned int*)&hb[(size_t)s * HC + 2 * lane];
        denom += p;
        acc0 += p * __uint_as_float(v << 16);
        acc1 += p * __uint_as_float(v & 0xffff0000u);
    }

    float inv = 1.f / (denom + 1e-16f);
    fx2 o2;
    o2.x = acc0 * inv + bias[2 * lane];
    o2.y = acc1 * inv + bias[2 * lane + 1];
    __builtin_nontemporal_store(o2, (fx2*)&out[(size_t)node * HC + 2 * lane]);
}

// ---------------------------------------------------------------------------
extern "C" void kernel_launch(void* const* d_in, const int* in_sizes, int n_in,
                              void* d_out, int out_size, void* d_ws, size_t ws_size,
                              hipStream_t stream)
{
    const float* x       = (const float*)d_in[0];
    const float* W       = (const float*)d_in[1];
    const float* att_src = (const float*)d_in[2];
    const float* att_dst = (const float*)d_in[3];
    const float* bias    = (const float*)d_in[4];
    const int*   ei      = (const int*)d_in[5];
    const int E = in_sizes[5] / 2;
    const int* srcp = ei;
    const int* dstp = ei + E;
    float* out = (float*)d_out;

    char* wsb = (char*)d_ws;
    size_t off = 0;
    auto alloc = [&](size_t bytes) -> char* {
        char* p = wsb + off;
        off += (bytes + 255) & ~(size_t)255;
        return p;
    };
    unsigned short* hb = (unsigned short*)alloc((size_t)N_NODES * HC * sizeof(unsigned short)); // 25.6 MB
    float* a_src   = (float*)alloc((size_t)N_NODES * NH * sizeof(float));
    float* a_dst   = (float*)alloc((size_t)N_NODES * NH * sizeof(float));
    int*   col     = (int*)alloc((size_t)(E + N_NODES) * sizeof(int));     // 6.8 MB
    int2*  rowse   = (int2*)alloc((size_t)N_NODES * sizeof(int2));         // 0.8 MB
    int*   deg     = (int*)alloc((size_t)N_NODES * sizeof(int));
    int*   dx      = (int*)alloc((size_t)N_NODES * sizeof(int));
    int*   cursor  = (int*)alloc((size_t)N_NODES * sizeof(int));
    int*   btot    = (int*)alloc(128 * sizeof(int));
    int*   bofs    = (int*)alloc(128 * sizeof(int));
    unsigned short* wt = (unsigned short*)alloc(128 * 128 * sizeof(unsigned short));

    (void)hipMemsetAsync(deg, 0, (size_t)N_NODES * sizeof(int), stream);

    const int egrid = (E + 2047) / 2048;

    k_prep<<<64, 256, 0, stream>>>(W, wt);
    k_gemm<<<(N_NODES + 63) / 64, 256, 0, stream>>>(x, wt, att_src, att_dst,
                                                    hb, a_src, a_dst);
    k_deg<<<egrid, 256, 0, stream>>>(dstp, deg, E);
    k_scanA<<<NSB, 1024, 0, stream>>>(deg, dx, btot);
    k_scanB<<<1, 128, 0, stream>>>(btot, bofs);
    k_scanC<<<NSB, 1024, 0, stream>>>(deg, dx, bofs, rowse, col, cursor);
    k_scatter<<<egrid, 256, 0, stream>>>(srcp, dstp, cursor, col, E);
    k_node<<<(N_NODES + 3) / 4, 256, 0, stream>>>(hb, a_src, a_dst, rowse, col, bias, out);
}

// Round 2
// 265.828 us; speedup vs baseline: 1.4342x; 1.4342x over previous
//
#include <hip/hip_runtime.h>
#include <hip/hip_bf16.h>
#include <math.h>

#define N_NODES 100000
#define F_IN    128
#define HC      128      // H*C
#define NH      4
#define SLOPE   0.2f

#define PADK    136      // LDS row stride in shorts (128 + 8 pad)

#define NB      196      // buckets = ceil(N/512)
#define BSH     9        // bucket = dst >> 9, local = dst & 511
#define CAP     10240    // per-bucket arena capacity (mean 8163, sigma ~90)
#define CHUNK   2048     // edges per k_bucket block (782 blocks -> ~3/CU)
#define CURPAD  16       // bucket_cursor stride in ints (64B: no false sharing)

typedef __attribute__((ext_vector_type(8))) short short8;   // bf16x8 MFMA frag
typedef __attribute__((ext_vector_type(4))) float f32x4;    // MFMA accum
typedef __attribute__((ext_vector_type(2))) float fx2;      // native float2 (NT store ok)

static __device__ __forceinline__ float leaky(float x) { return x > 0.f ? x : SLOPE * x; }

static __device__ __forceinline__ short f2bs(float f) {
    __hip_bfloat16 b = __float2bfloat16(f);   // RTN-even
    return *reinterpret_cast<short*>(&b);
}

// ---------------------------------------------------------------------------
// K0: one-time W conversion: W[k][n] fp32 -> wt[n][k] bf16 (n-major, k inner)
// ---------------------------------------------------------------------------
__global__ __launch_bounds__(256) void k_prep(const float* __restrict__ W,
                                              unsigned short* __restrict__ wt)
{
    int t = blockIdx.x * 256 + threadIdx.x;
    if (t < 128 * 128) {
        int k = t >> 7, n = t & 127;
        wt[n * 128 + k] = (unsigned short)f2bs(W[k * HC + n]);
    }
}

// ---------------------------------------------------------------------------
// K1: h = x @ W via bf16 MFMA (fp32 accum). Block = 64 rows x 128 cols,
// 4 waves; 8 n-tiles x 4 k-blocks of mfma_f32_16x16x32_bf16.
// Epilogue: bf16 h store + fp32 a_src/a_dst (per-head dot + shfl tree).
// ---------------------------------------------------------------------------
__global__ __launch_bounds__(256) void k_gemm(const float* __restrict__ x,
                                              const unsigned short* __restrict__ wt,
                                              const float* __restrict__ att_src,
                                              const float* __restrict__ att_dst,
                                              unsigned short* __restrict__ hb,
                                              float* __restrict__ a_src,
                                              float* __restrict__ a_dst)
{
    __shared__ short xs[64 * PADK];    // bf16 x tile [row][k]   17.4 KB
    __shared__ short ws[128 * PADK];   // bf16 W^T    [n][k]     34.8 KB
    const int t  = threadIdx.x;
    const int r0 = blockIdx.x * 64;

    // stage x tile (fp32 -> bf16): 64 rows x 32 float4 chunks
    for (int i = t; i < 2048; i += 256) {
        int row = i >> 5, kq = (i & 31) * 4;
        int gr = r0 + row;
        float4 v = make_float4(0.f, 0.f, 0.f, 0.f);
        if (gr < N_NODES) v = ((const float4*)(x + (size_t)gr * F_IN))[i & 31];
        short* p = &xs[row * PADK + kq];
        p[0] = f2bs(v.x); p[1] = f2bs(v.y); p[2] = f2bs(v.z); p[3] = f2bs(v.w);
    }
    // stage W^T (bf16 copy): thread i copies 16B; global reads fully contiguous
    for (int i = t; i < 2048; i += 256) {
        int n = i >> 4, k0 = (i & 15) * 8;
        *(float4*)&ws[n * PADK + k0] = *(const float4*)&wt[n * 128 + k0];
    }
    __syncthreads();

    const int wave = t >> 6, lane = t & 63;
    const int quad = lane >> 4, l16 = lane & 15;
    const int wrow = wave * 16;

    f32x4 acc[8];
    #pragma unroll
    for (int nt = 0; nt < 8; ++nt) acc[nt] = (f32x4){0.f, 0.f, 0.f, 0.f};

    const short* ap = &xs[(wrow + l16) * PADK + quad * 8];
    #pragma unroll
    for (int kb = 0; kb < 4; ++kb) {
        short8 a = *(const short8*)(ap + kb * 32);
        #pragma unroll
        for (int nt = 0; nt < 8; ++nt) {
            short8 b = *(const short8*)&ws[(nt * 16 + l16) * PADK + kb * 32 + quad * 8];
            acc[nt] = __builtin_amdgcn_mfma_f32_16x16x32_bf16(a, b, acc[nt], 0, 0, 0);
        }
    }

    float att_s[8], att_d[8];
    #pragma unroll
    for (int nt = 0; nt < 8; ++nt) {
        att_s[nt] = att_src[nt * 16 + l16];
        att_d[nt] = att_dst[nt * 16 + l16];
    }

    #pragma unroll
    for (int g = 0; g < 4; ++g) {
        int r = r0 + wrow + quad * 4 + g;
        if (r < N_NODES) {
            #pragma unroll
            for (int nt = 0; nt < 8; ++nt)
                hb[(size_t)r * HC + nt * 16 + l16] = (unsigned short)f2bs(acc[nt][g]);
        }
        float s0 = acc[0][g] * att_s[0] + acc[1][g] * att_s[1];
        float s1 = acc[2][g] * att_s[2] + acc[3][g] * att_s[3];
        float s2 = acc[4][g] * att_s[4] + acc[5][g] * att_s[5];
        float s3 = acc[6][g] * att_s[6] + acc[7][g] * att_s[7];
        float d0 = acc[0][g] * att_d[0] + acc[1][g] * att_d[1];
        float d1 = acc[2][g] * att_d[2] + acc[3][g] * att_d[3];
        float d2 = acc[4][g] * att_d[4] + acc[5][g] * att_d[5];
        float d3 = acc[6][g] * att_d[6] + acc[7][g] * att_d[7];
        #pragma unroll
        for (int o = 1; o < 16; o <<= 1) {
            s0 += __shfl_xor(s0, o); s1 += __shfl_xor(s1, o);
            s2 += __shfl_xor(s2, o); s3 += __shfl_xor(s3, o);
            d0 += __shfl_xor(d0, o); d1 += __shfl_xor(d1, o);
            d2 += __shfl_xor(d2, o); d3 += __shfl_xor(d3, o);
        }
        if (l16 == 0 && r < N_NODES) {
            *(float4*)&a_src[r * NH] = make_float4(s0, s1, s2, s3);
            *(float4*)&a_dst[r * NH] = make_float4(d0, d1, d2, d3);
        }
    }
}

// ---------------------------------------------------------------------------
// K2: multisplit edges into NB dst-buckets via LDS staging; dense flushes.
// eb[bucket*CAP + k] = (src<<9) | (dst&511). Self-loops never bucketed.
// CHUNK=2048 -> 782 blocks (~3/CU resident). Global base atomics: one per
// (block,bucket), to 64B-padded counters -> no false sharing.
// ---------------------------------------------------------------------------
__global__ __launch_bounds__(256) void k_bucket(const int* __restrict__ srcp,
                                                const int* __restrict__ dstp,
                                                int* __restrict__ bucket_cursor,
                                                int* __restrict__ eb, int E)
{
    __shared__ int ebuf[CHUNK];
    __shared__ unsigned char bkt[CHUNK];
    __shared__ int hist[256];
    __shared__ int lexcl[257];
    __shared__ int gbase[256];
    __shared__ int sdata[256];

    const int t = threadIdx.x;
    const int base = blockIdx.x * CHUNK;

    hist[t] = 0;
    __syncthreads();

    #pragma unroll
    for (int j = 0; j < CHUNK / 256; ++j) {
        int i = base + t + j * 256;
        if (i < E) atomicAdd(&hist[dstp[i] >> BSH], 1);
    }
    __syncthreads();

    int cnt = hist[t];
    sdata[t] = cnt;
    __syncthreads();
    for (int o = 1; o < 256; o <<= 1) {
        int add = (t >= o) ? sdata[t - o] : 0;
        __syncthreads();
        sdata[t] += add;
        __syncthreads();
    }
    int excl = sdata[t] - cnt;
    lexcl[t] = excl;
    if (t == 255) lexcl[256] = sdata[255];
    hist[t] = excl;
    int gb = 0;
    if (t < NB && cnt > 0) gb = atomicAdd(&bucket_cursor[t * CURPAD], cnt);
    gbase[t] = t * CAP + gb;
    __syncthreads();

    #pragma unroll
    for (int j = 0; j < CHUNK / 256; ++j) {
        int i = base + t + j * 256;
        if (i < E) {
            int s = srcp[i], d = dstp[i];
            int b = d >> BSH;
            int r = atomicAdd(&hist[b], 1);
            ebuf[r] = (s << BSH) | (d & 511);
            bkt[r] = (unsigned char)b;
        }
    }
    __syncthreads();

    const int blockTotal = lexcl[256];
    for (int i = t; i < blockTotal; i += 256) {
        int b = bkt[i];
        eb[gbase[b] + (i - lexcl[b])] = ebuf[i];
    }
}

// ---------------------------------------------------------------------------
// K3: exclusive scan of bucket counts (+ self-loops) -> bexcl
// ---------------------------------------------------------------------------
__global__ void k_bscan(const int* __restrict__ bucket_cursor,
                        int* __restrict__ bexcl)
{
    __shared__ int sdata[256];
    const int t = threadIdx.x;
    int nvalid = 0;
    if (t < NB) {
        int n0 = t * 512;
        nvalid = min(512, N_NODES - n0);
        if (nvalid < 0) nvalid = 0;
    }
    int v = (t < NB) ? bucket_cursor[t * CURPAD] + nvalid : 0;
    sdata[t] = v;
    __syncthreads();
    for (int o = 1; o < 256; o <<= 1) {
        int add = (t >= o) ? sdata[t - o] : 0;
        __syncthreads();
        sdata[t] += add;
        __syncthreads();
    }
    if (t < NB) bexcl[t] = sdata[t] - v;
}

// ---------------------------------------------------------------------------
// K4: per-bucket CSR build, 1024 threads/block (16 waves/CU on 196 CUs).
// LDS histogram + 256-wide scan; self-loop at slot 0.
// ---------------------------------------------------------------------------
__global__ __launch_bounds__(1024) void k_csr(const int* __restrict__ eb,
                                              const int* __restrict__ bucket_cursor,
                                              const int* __restrict__ bexcl,
                                              int* __restrict__ col,
                                              int2* __restrict__ rowse)
{
    __shared__ int deg[512];
    __shared__ int sdata[256];

    const int t  = threadIdx.x;
    const int b  = blockIdx.x;
    const int n0 = b * 512;
    const int cnt   = bucket_cursor[b * CURPAD];
    const int ebase = b * CAP;
    const int gofs  = bexcl[b];

    if (t < 512) deg[t] = (n0 + t < N_NODES) ? 1 : 0;
    __syncthreads();

    for (int i = t; i < cnt; i += 1024)
        atomicAdd(&deg[eb[ebase + i] & 511], 1);
    __syncthreads();

    int d0 = 0, d1 = 0, ps = 0;
    if (t < 256) {
        d0 = deg[2 * t]; d1 = deg[2 * t + 1];
        ps = d0 + d1;
        sdata[t] = ps;
    }
    __syncthreads();
    for (int o = 1; o < 256; o <<= 1) {
        int add = 0;
        if (t < 256 && t >= o) add = sdata[t - o];
        __syncthreads();
        if (t < 256) sdata[t] += add;
        __syncthreads();
    }
    if (t < 256) {
        int e0 = sdata[t] - ps;
        int e1 = e0 + d0;
        int na = n0 + 2 * t, nb2 = n0 + 2 * t + 1;
        if (na < N_NODES) {
            rowse[na] = make_int2(gofs + e0, gofs + e0 + d0);
            col[gofs + e0] = na;
        }
        if (nb2 < N_NODES) {
            rowse[nb2] = make_int2(gofs + e1, gofs + e1 + d1);
            col[gofs + e1] = nb2;
        }
        deg[2 * t]     = e0 + 1;
        deg[2 * t + 1] = e1 + 1;
    }
    __syncthreads();

    for (int i = t; i < cnt; i += 1024) {
        int v = eb[ebase + i];
        int r = atomicAdd(&deg[v & 511], 1);
        col[gofs + r] = v >> BSH;
    }
}

// ---------------------------------------------------------------------------
// K5: per-dst-node softmax + aggregation. One wave per node; bf16 h gathers,
// x8 unroll; non-temporal out stores. (unchanged — isolates CSR-build fix)
// ---------------------------------------------------------------------------
__global__ __launch_bounds__(256) void k_node(const unsigned short* __restrict__ hb,
                                              const float* __restrict__ a_src,
                                              const float* __restrict__ a_dst,
                                              const int2* __restrict__ rowse,
                                              const int* __restrict__ col,
                                              const float* __restrict__ bias,
                                              float* __restrict__ out)
{
    const int lane = threadIdx.x & 63;
    const int node = blockIdx.x * 4 + (threadIdx.x >> 6);
    if (node >= N_NODES) return;

    const int2 se = rowse[node];
    const int r0 = se.x, r1 = se.y;
    const int myh = lane >> 4;
    const float adm = a_dst[node * NH + myh];

    float denom = 0.f, acc0 = 0.f, acc1 = 0.f;
    int i = r0;
    for (; i + 8 <= r1; i += 8) {
        int s[8];
        #pragma unroll
        for (int j = 0; j < 8; ++j) s[j] = col[i + j];
        float as[8];
        #pragma unroll
        for (int j = 0; j < 8; ++j) as[j] = a_src[s[j] * NH + myh];
        unsigned int hv[8];
        #pragma unroll
        for (int j = 0; j < 8; ++j)
            hv[j] = *(const unsigned int*)&hb[(size_t)s[j] * HC + 2 * lane];
        #pragma unroll
        for (int j = 0; j < 8; ++j) {
            float p = __expf(leaky(as[j] + adm));
            denom += p;
            acc0 += p * __uint_as_float(hv[j] << 16);
            acc1 += p * __uint_as_float(hv[j] & 0xffff0000u);
        }
    }
    for (; i < r1; ++i) {
        int s = col[i];
        float p = __expf(leaky(a_src[s * NH + myh] + adm));
        unsigned int v = *(const unsigned int*)&hb[(size_t)s * HC + 2 * lane];
        denom += p;
        acc0 += p * __uint_as_float(v << 16);
        acc1 += p * __uint_as_float(v & 0xffff0000u);
    }

    float inv = 1.f / (denom + 1e-16f);
    fx2 o2;
    o2.x = acc0 * inv + bias[2 * lane];
    o2.y = acc1 * inv + bias[2 * lane + 1];
    __builtin_nontemporal_store(o2, (fx2*)&out[(size_t)node * HC + 2 * lane]);
}

// ---------------------------------------------------------------------------
extern "C" void kernel_launch(void* const* d_in, const int* in_sizes, int n_in,
                              void* d_out, int out_size, void* d_ws, size_t ws_size,
                              hipStream_t stream)
{
    const float* x       = (const float*)d_in[0];
    const float* W       = (const float*)d_in[1];
    const float* att_src = (const float*)d_in[2];
    const float* att_dst = (const float*)d_in[3];
    const float* bias    = (const float*)d_in[4];
    const int*   ei      = (const int*)d_in[5];
    const int E = in_sizes[5] / 2;
    const int* srcp = ei;
    const int* dstp = ei + E;
    float* out = (float*)d_out;

    char* wsb = (char*)d_ws;
    size_t off = 0;
    auto alloc = [&](size_t bytes) -> char* {
        char* p = wsb + off;
        off += (bytes + 255) & ~(size_t)255;
        return p;
    };
    unsigned short* hb = (unsigned short*)alloc((size_t)N_NODES * HC * sizeof(unsigned short)); // 25.6 MB
    float* a_src   = (float*)alloc((size_t)N_NODES * NH * sizeof(float));
    float* a_dst   = (float*)alloc((size_t)N_NODES * NH * sizeof(float));
    int*   eb      = (int*)alloc((size_t)NB * CAP * sizeof(int));          // 8.0 MB
    int*   col     = (int*)alloc((size_t)(E + N_NODES) * sizeof(int));     // 6.8 MB
    int2*  rowse   = (int2*)alloc((size_t)N_NODES * sizeof(int2));         // 0.8 MB
    int*   bcursor = (int*)alloc((size_t)NB * CURPAD * sizeof(int));       // 12.5 KB padded
    int*   bexcl   = (int*)alloc(256 * sizeof(int));
    unsigned short* wt = (unsigned short*)alloc(128 * 128 * sizeof(unsigned short));

    (void)hipMemsetAsync(bcursor, 0, (size_t)NB * CURPAD * sizeof(int), stream);

    k_prep<<<64, 256, 0, stream>>>(W, wt);
    k_gemm<<<(N_NODES + 63) / 64, 256, 0, stream>>>(x, wt, att_src, att_dst,
                                                    hb, a_src, a_dst);
    k_bucket<<<(E + CHUNK - 1) / CHUNK, 256, 0, stream>>>(srcp, dstp, bcursor, eb, E);
    k_bscan<<<1, 256, 0, stream>>>(bcursor, bexcl);
    k_csr<<<NB, 1024, 0, stream>>>(eb, bcursor, bexcl, col, rowse);
    k_node<<<(N_NODES + 3) / 4, 256, 0, stream>>>(hb, a_src, a_dst, rowse, col, bias, out);
}

// Round 3
// 251.047 us; speedup vs baseline: 1.5186x; 1.0589x over previous
//
#include <hip/hip_runtime.h>
#include <hip/hip_bf16.h>
#include <math.h>

#define N_NODES 100000
#define F_IN    128
#define HC      128      // H*C
#define NH      4
#define SLOPE   0.2f

#define PADK    136      // LDS row stride in shorts (128 + 8 pad)

#define NB      196      // buckets = ceil(N/512)
#define BSH     9        // bucket = dst >> 9, local = dst & 511
#define CAP     10240    // per-bucket edge arena capacity (mean 8163, sigma ~90)
#define CAPC    10752    // per-bucket col arena (CAP + 512 self-loops)
#define CHUNK   2048     // edges per bucket block
#define CURPAD  16       // bucket_cursor stride in ints (64B: no false sharing)

#define GEMM_BLOCKS 1563 // ceil(N/64)

typedef __attribute__((ext_vector_type(8))) short short8;   // bf16x8 MFMA frag
typedef __attribute__((ext_vector_type(4))) float f32x4;    // MFMA accum
typedef __attribute__((ext_vector_type(2))) float fx2;      // native float2 (NT store ok)

static __device__ __forceinline__ float leaky(float x) { return x > 0.f ? x : SLOPE * x; }

static __device__ __forceinline__ short f2bs(float f) {
    __hip_bfloat16 b = __float2bfloat16(f);   // RTN-even
    return *reinterpret_cast<short*>(&b);
}

// ---------------------------------------------------------------------------
// K0: one-time W conversion W[k][n] fp32 -> wt[n][k] bf16, AND zero the
// bucket cursors (replaces the hipMemsetAsync dispatch).
// ---------------------------------------------------------------------------
__global__ __launch_bounds__(256) void k_pre(const float* __restrict__ W,
                                             unsigned short* __restrict__ wt,
                                             int* __restrict__ bucket_cursor)
{
    int t = blockIdx.x * 256 + threadIdx.x;
    if (t < 128 * 128) {
        int k = t >> 7, n = t & 127;
        wt[n * 128 + k] = (unsigned short)f2bs(W[k * HC + n]);
    }
    if (t < NB * CURPAD) bucket_cursor[t] = 0;
}

// ---------------------------------------------------------------------------
// K1 (fused): blocks [0, GEMM_BLOCKS) = GEMM; rest = edge multisplit.
// The two halves are fully independent (disjoint inputs/outputs), so fusing
// them removes one dispatch boundary and co-schedules MFMA-bound gemm blocks
// with memory-bound bucket blocks across the CUs.
// LDS is a union: gemm needs 52.2 KB, bucket 14.3 KB -> 3 blocks/CU either way.
// ---------------------------------------------------------------------------
union SMem {
    struct {
        short xs[64 * PADK];     // bf16 x tile [row][k]   17.4 KB
        short ws[128 * PADK];    // bf16 W^T    [n][k]     34.8 KB
    } g;
    struct {
        int ebuf[CHUNK];
        unsigned char bkt[CHUNK];
        int hist[256];
        int lexcl[257];
        int gbase[256];
        int sdata[256];
    } b;
};

__global__ __launch_bounds__(256) void k_main(const float* __restrict__ x,
                                              const unsigned short* __restrict__ wt,
                                              const float* __restrict__ att_src,
                                              const float* __restrict__ att_dst,
                                              unsigned short* __restrict__ hb,
                                              float* __restrict__ a_src,
                                              float* __restrict__ a_dst,
                                              const int* __restrict__ srcp,
                                              const int* __restrict__ dstp,
                                              int* __restrict__ bucket_cursor,
                                              int* __restrict__ eb, int E)
{
    __shared__ SMem sm;
    const int t = threadIdx.x;

    if (blockIdx.x < GEMM_BLOCKS) {
        // ------------------------------ GEMM ------------------------------
        const int r0 = blockIdx.x * 64;

        for (int i = t; i < 2048; i += 256) {
            int row = i >> 5, kq = (i & 31) * 4;
            int gr = r0 + row;
            float4 v = make_float4(0.f, 0.f, 0.f, 0.f);
            if (gr < N_NODES) v = ((const float4*)(x + (size_t)gr * F_IN))[i & 31];
            short* p = &sm.g.xs[row * PADK + kq];
            p[0] = f2bs(v.x); p[1] = f2bs(v.y); p[2] = f2bs(v.z); p[3] = f2bs(v.w);
        }
        for (int i = t; i < 2048; i += 256) {
            int n = i >> 4, k0 = (i & 15) * 8;
            *(float4*)&sm.g.ws[n * PADK + k0] = *(const float4*)&wt[n * 128 + k0];
        }
        __syncthreads();

        const int wave = t >> 6, lane = t & 63;
        const int quad = lane >> 4, l16 = lane & 15;
        const int wrow = wave * 16;

        f32x4 acc[8];
        #pragma unroll
        for (int nt = 0; nt < 8; ++nt) acc[nt] = (f32x4){0.f, 0.f, 0.f, 0.f};

        const short* ap = &sm.g.xs[(wrow + l16) * PADK + quad * 8];
        #pragma unroll
        for (int kb = 0; kb < 4; ++kb) {
            short8 a = *(const short8*)(ap + kb * 32);
            #pragma unroll
            for (int nt = 0; nt < 8; ++nt) {
                short8 b = *(const short8*)&sm.g.ws[(nt * 16 + l16) * PADK + kb * 32 + quad * 8];
                acc[nt] = __builtin_amdgcn_mfma_f32_16x16x32_bf16(a, b, acc[nt], 0, 0, 0);
            }
        }

        float att_s[8], att_d[8];
        #pragma unroll
        for (int nt = 0; nt < 8; ++nt) {
            att_s[nt] = att_src[nt * 16 + l16];
            att_d[nt] = att_dst[nt * 16 + l16];
        }

        #pragma unroll
        for (int g = 0; g < 4; ++g) {
            int r = r0 + wrow + quad * 4 + g;
            if (r < N_NODES) {
                #pragma unroll
                for (int nt = 0; nt < 8; ++nt)
                    hb[(size_t)r * HC + nt * 16 + l16] = (unsigned short)f2bs(acc[nt][g]);
            }
            float s0 = acc[0][g] * att_s[0] + acc[1][g] * att_s[1];
            float s1 = acc[2][g] * att_s[2] + acc[3][g] * att_s[3];
            float s2 = acc[4][g] * att_s[4] + acc[5][g] * att_s[5];
            float s3 = acc[6][g] * att_s[6] + acc[7][g] * att_s[7];
            float d0 = acc[0][g] * att_d[0] + acc[1][g] * att_d[1];
            float d1 = acc[2][g] * att_d[2] + acc[3][g] * att_d[3];
            float d2 = acc[4][g] * att_d[4] + acc[5][g] * att_d[5];
            float d3 = acc[6][g] * att_d[6] + acc[7][g] * att_d[7];
            #pragma unroll
            for (int o = 1; o < 16; o <<= 1) {
                s0 += __shfl_xor(s0, o); s1 += __shfl_xor(s1, o);
                s2 += __shfl_xor(s2, o); s3 += __shfl_xor(s3, o);
                d0 += __shfl_xor(d0, o); d1 += __shfl_xor(d1, o);
                d2 += __shfl_xor(d2, o); d3 += __shfl_xor(d3, o);
            }
            if (l16 == 0 && r < N_NODES) {
                *(float4*)&a_src[r * NH] = make_float4(s0, s1, s2, s3);
                *(float4*)&a_dst[r * NH] = make_float4(d0, d1, d2, d3);
            }
        }
    } else {
        // ---------------------------- multisplit --------------------------
        const int base = (blockIdx.x - GEMM_BLOCKS) * CHUNK;

        sm.b.hist[t] = 0;
        __syncthreads();

        #pragma unroll
        for (int j = 0; j < CHUNK / 256; ++j) {
            int i = base + t + j * 256;
            if (i < E) atomicAdd(&sm.b.hist[dstp[i] >> BSH], 1);
        }
        __syncthreads();

        int cnt = sm.b.hist[t];
        sm.b.sdata[t] = cnt;
        __syncthreads();
        for (int o = 1; o < 256; o <<= 1) {
            int add = (t >= o) ? sm.b.sdata[t - o] : 0;
            __syncthreads();
            sm.b.sdata[t] += add;
            __syncthreads();
        }
        int excl = sm.b.sdata[t] - cnt;
        sm.b.lexcl[t] = excl;
        if (t == 255) sm.b.lexcl[256] = sm.b.sdata[255];
        sm.b.hist[t] = excl;
        int gb = 0;
        if (t < NB && cnt > 0) gb = atomicAdd(&bucket_cursor[t * CURPAD], cnt);
        sm.b.gbase[t] = t * CAP + gb;
        __syncthreads();

        #pragma unroll
        for (int j = 0; j < CHUNK / 256; ++j) {
            int i = base + t + j * 256;
            if (i < E) {
                int s = srcp[i], d = dstp[i];
                int b = d >> BSH;
                int r = atomicAdd(&sm.b.hist[b], 1);
                sm.b.ebuf[r] = (s << BSH) | (d & 511);
                sm.b.bkt[r] = (unsigned char)b;
            }
        }
        __syncthreads();

        const int blockTotal = sm.b.lexcl[256];
        for (int i = t; i < blockTotal; i += 256) {
            int b = sm.b.bkt[i];
            eb[sm.b.gbase[b] + (i - sm.b.lexcl[b])] = sm.b.ebuf[i];
        }
    }
}

// ---------------------------------------------------------------------------
// K2: per-bucket CSR build, 1024 threads/block, FIXED per-bucket col arena
// (gofs = b*CAPC) -> no global bucket scan needed. Self-loop at slot 0.
// ---------------------------------------------------------------------------
__global__ __launch_bounds__(1024) void k_csr(const int* __restrict__ eb,
                                              const int* __restrict__ bucket_cursor,
                                              int* __restrict__ col,
                                              int2* __restrict__ rowse)
{
    __shared__ int deg[512];
    __shared__ int sdata[256];

    const int t  = threadIdx.x;
    const int b  = blockIdx.x;
    const int n0 = b * 512;
    const int cnt   = bucket_cursor[b * CURPAD];
    const int ebase = b * CAP;
    const int gofs  = b * CAPC;

    if (t < 512) deg[t] = (n0 + t < N_NODES) ? 1 : 0;
    __syncthreads();

    for (int i = t; i < cnt; i += 1024)
        atomicAdd(&deg[eb[ebase + i] & 511], 1);
    __syncthreads();

    int d0 = 0, d1 = 0, ps = 0;
    if (t < 256) {
        d0 = deg[2 * t]; d1 = deg[2 * t + 1];
        ps = d0 + d1;
        sdata[t] = ps;
    }
    __syncthreads();
    for (int o = 1; o < 256; o <<= 1) {
        int add = 0;
        if (t < 256 && t >= o) add = sdata[t - o];
        __syncthreads();
        if (t < 256) sdata[t] += add;
        __syncthreads();
    }
    if (t < 256) {
        int e0 = sdata[t] - ps;
        int e1 = e0 + d0;
        int na = n0 + 2 * t, nb2 = n0 + 2 * t + 1;
        if (na < N_NODES) {
            rowse[na] = make_int2(gofs + e0, gofs + e0 + d0);
            col[gofs + e0] = na;
        }
        if (nb2 < N_NODES) {
            rowse[nb2] = make_int2(gofs + e1, gofs + e1 + d1);
            col[gofs + e1] = nb2;
        }
        deg[2 * t]     = e0 + 1;
        deg[2 * t + 1] = e1 + 1;
    }
    __syncthreads();

    for (int i = t; i < cnt; i += 1024) {
        int v = eb[ebase + i];
        int r = atomicAdd(&deg[v & 511], 1);
        col[gofs + r] = v >> BSH;
    }
}

// ---------------------------------------------------------------------------
// K3: per-dst-node softmax + aggregation. One wave per node; bf16 h gathers,
// x8 unroll; non-temporal out stores. (unchanged — clean attribution)
// ---------------------------------------------------------------------------
__global__ __launch_bounds__(256) void k_node(const unsigned short* __restrict__ hb,
                                              const float* __restrict__ a_src,
                                              const float* __restrict__ a_dst,
                                              const int2* __restrict__ rowse,
                                              const int* __restrict__ col,
                                              const float* __restrict__ bias,
                                              float* __restrict__ out)
{
    const int lane = threadIdx.x & 63;
    const int node = blockIdx.x * 4 + (threadIdx.x >> 6);
    if (node >= N_NODES) return;

    const int2 se = rowse[node];
    const int r0 = se.x, r1 = se.y;
    const int myh = lane >> 4;
    const float adm = a_dst[node * NH + myh];

    float denom = 0.f, acc0 = 0.f, acc1 = 0.f;
    int i = r0;
    for (; i + 8 <= r1; i += 8) {
        int s[8];
        #pragma unroll
        for (int j = 0; j < 8; ++j) s[j] = col[i + j];
        float as[8];
        #pragma unroll
        for (int j = 0; j < 8; ++j) as[j] = a_src[s[j] * NH + myh];
        unsigned int hv[8];
        #pragma unroll
        for (int j = 0; j < 8; ++j)
            hv[j] = *(const unsigned int*)&hb[(size_t)s[j] * HC + 2 * lane];
        #pragma unroll
        for (int j = 0; j < 8; ++j) {
            float p = __expf(leaky(as[j] + adm));
            denom += p;
            acc0 += p * __uint_as_float(hv[j] << 16);
            acc1 += p * __uint_as_float(hv[j] & 0xffff0000u);
        }
    }
    for (; i < r1; ++i) {
        int s = col[i];
        float p = __expf(leaky(a_src[s * NH + myh] + adm));
        unsigned int v = *(const unsigned int*)&hb[(size_t)s * HC + 2 * lane];
        denom += p;
        acc0 += p * __uint_as_float(v << 16);
        acc1 += p * __uint_as_float(v & 0xffff0000u);
    }

    float inv = 1.f / (denom + 1e-16f);
    fx2 o2;
    o2.x = acc0 * inv + bias[2 * lane];
    o2.y = acc1 * inv + bias[2 * lane + 1];
    __builtin_nontemporal_store(o2, (fx2*)&out[(size_t)node * HC + 2 * lane]);
}

// ---------------------------------------------------------------------------
extern "C" void kernel_launch(void* const* d_in, const int* in_sizes, int n_in,
                              void* d_out, int out_size, void* d_ws, size_t ws_size,
                              hipStream_t stream)
{
    const float* x       = (const float*)d_in[0];
    const float* W       = (const float*)d_in[1];
    const float* att_src = (const float*)d_in[2];
    const float* att_dst = (const float*)d_in[3];
    const float* bias    = (const float*)d_in[4];
    const int*   ei      = (const int*)d_in[5];
    const int E = in_sizes[5] / 2;
    const int* srcp = ei;
    const int* dstp = ei + E;
    float* out = (float*)d_out;

    char* wsb = (char*)d_ws;
    size_t off = 0;
    auto alloc = [&](size_t bytes) -> char* {
        char* p = wsb + off;
        off += (bytes + 255) & ~(size_t)255;
        return p;
    };
    unsigned short* hb = (unsigned short*)alloc((size_t)N_NODES * HC * sizeof(unsigned short)); // 25.6 MB
    float* a_src   = (float*)alloc((size_t)N_NODES * NH * sizeof(float));
    float* a_dst   = (float*)alloc((size_t)N_NODES * NH * sizeof(float));
    int*   eb      = (int*)alloc((size_t)NB * CAP * sizeof(int));          // 8.0 MB
    int*   col     = (int*)alloc((size_t)NB * CAPC * sizeof(int));         // 8.4 MB
    int2*  rowse   = (int2*)alloc((size_t)N_NODES * sizeof(int2));         // 0.8 MB
    int*   bcursor = (int*)alloc((size_t)NB * CURPAD * sizeof(int));       // 12.5 KB padded
    unsigned short* wt = (unsigned short*)alloc(128 * 128 * sizeof(unsigned short));

    const int bucketBlocks = (E + CHUNK - 1) / CHUNK;

    k_pre<<<64, 256, 0, stream>>>(W, wt, bcursor);
    k_main<<<GEMM_BLOCKS + bucketBlocks, 256, 0, stream>>>(x, wt, att_src, att_dst,
                                                           hb, a_src, a_dst,
                                                           srcp, dstp, bcursor, eb, E);
    k_csr<<<NB, 1024, 0, stream>>>(eb, bcursor, col, rowse);
    k_node<<<(N_NODES + 3) / 4, 256, 0, stream>>>(hb, a_src, a_dst, rowse, col, bias, out);
}

// Round 5
// 247.426 us; speedup vs baseline: 1.5408x; 1.0146x over previous
//
#include <hip/hip_runtime.h>
#include <hip/hip_bf16.h>
#include <math.h>

#define N_NODES 100000
#define F_IN    128
#define HC      128      // H*C
#define NH      4
#define SLOPE   0.2f

#define PADK    136      // LDS row stride in shorts (128 + 8 pad)

#define NB      196      // buckets = ceil(N/512)
#define BSH     9        // bucket = dst >> 9, local = dst & 511
#define CAP     10240    // per-bucket edge arena capacity (mean 8163, sigma ~90)
#define CAPC    10752    // per-bucket col arena (CAP + 512 self-loops)
#define CHUNK   2048     // edges per bucket block
#define CURPAD  16       // bucket_cursor stride in ints (64B: no false sharing)

typedef __attribute__((ext_vector_type(8))) short short8;   // bf16x8 MFMA frag
typedef __attribute__((ext_vector_type(4))) float f32x4;    // MFMA accum / native float4 (NT store ok)

static __device__ __forceinline__ float leaky(float x) { return x > 0.f ? x : SLOPE * x; }

static __device__ __forceinline__ short f2bs(float f) {
    __hip_bfloat16 b = __float2bfloat16(f);   // RTN-even
    return *reinterpret_cast<short*>(&b);
}

// ---------------------------------------------------------------------------
// K0: one-time W conversion W[k][n] fp32 -> wt[n][k] bf16, AND zero the
// bucket cursors (replaces the hipMemsetAsync dispatch).
// ---------------------------------------------------------------------------
__global__ __launch_bounds__(256) void k_pre(const float* __restrict__ W,
                                             unsigned short* __restrict__ wt,
                                             int* __restrict__ bucket_cursor)
{
    int t = blockIdx.x * 256 + threadIdx.x;
    if (t < 128 * 128) {
        int k = t >> 7, n = t & 127;
        wt[n * 128 + k] = (unsigned short)f2bs(W[k * HC + n]);
    }
    if (t < NB * CURPAD) bucket_cursor[t] = 0;
}

// ---------------------------------------------------------------------------
// K1: multisplit edges into NB dst-buckets via LDS staging; dense flushes.
// eb[bucket*CAP + k] = (src<<9) | (dst&511). 782 blocks (~3/CU resident).
// ---------------------------------------------------------------------------
__global__ __launch_bounds__(256) void k_bucket(const int* __restrict__ srcp,
                                                const int* __restrict__ dstp,
                                                int* __restrict__ bucket_cursor,
                                                int* __restrict__ eb, int E)
{
    __shared__ int ebuf[CHUNK];
    __shared__ unsigned char bkt[CHUNK];
    __shared__ int hist[256];
    __shared__ int lexcl[257];
    __shared__ int gbase[256];
    __shared__ int sdata[256];

    const int t = threadIdx.x;
    const int base = blockIdx.x * CHUNK;

    hist[t] = 0;
    __syncthreads();

    #pragma unroll
    for (int j = 0; j < CHUNK / 256; ++j) {
        int i = base + t + j * 256;
        if (i < E) atomicAdd(&hist[dstp[i] >> BSH], 1);
    }
    __syncthreads();

    int cnt = hist[t];
    sdata[t] = cnt;
    __syncthreads();
    for (int o = 1; o < 256; o <<= 1) {
        int add = (t >= o) ? sdata[t - o] : 0;
        __syncthreads();
        sdata[t] += add;
        __syncthreads();
    }
    int excl = sdata[t] - cnt;
    lexcl[t] = excl;
    if (t == 255) lexcl[256] = sdata[255];
    hist[t] = excl;
    int gb = 0;
    if (t < NB && cnt > 0) gb = atomicAdd(&bucket_cursor[t * CURPAD], cnt);
    gbase[t] = t * CAP + gb;
    __syncthreads();

    #pragma unroll
    for (int j = 0; j < CHUNK / 256; ++j) {
        int i = base + t + j * 256;
        if (i < E) {
            int s = srcp[i], d = dstp[i];
            int b = d >> BSH;
            int r = atomicAdd(&hist[b], 1);
            ebuf[r] = (s << BSH) | (d & 511);
            bkt[r] = (unsigned char)b;
        }
    }
    __syncthreads();

    const int blockTotal = lexcl[256];
    for (int i = t; i < blockTotal; i += 256) {
        int b = bkt[i];
        eb[gbase[b] + (i - lexcl[b])] = ebuf[i];
    }
}

// ---------------------------------------------------------------------------
// K2 (fused): blocks [0, NB) = per-bucket CSR build (latency-bound, hides
// under gemm); blocks [NB, NB+1563) = GEMM. csr blocks FIRST so they start
// at t=0 and overlap the whole gemm phase.
// LDS union: gemm 52.2 KB, csr 3 KB.
// ---------------------------------------------------------------------------
union SMem {
    struct {
        short xs[64 * PADK];     // bf16 x tile [row][k]   17.4 KB
        short ws[128 * PADK];    // bf16 W^T    [n][k]     34.8 KB
    } g;
    struct {
        int deg[512];
        int sdata[256];
    } c;
};

__global__ __launch_bounds__(256) void k_fused(const float* __restrict__ x,
                                               const unsigned short* __restrict__ wt,
                                               const float* __restrict__ att_src,
                                               const float* __restrict__ att_dst,
                                               unsigned short* __restrict__ hb,
                                               float* __restrict__ a_src,
                                               float* __restrict__ a_dst,
                                               const int* __restrict__ eb,
                                               const int* __restrict__ bucket_cursor,
                                               int* __restrict__ col,
                                               int2* __restrict__ rowse)
{
    __shared__ SMem sm;
    const int t = threadIdx.x;

    if (blockIdx.x < NB) {
        // ------------------------- per-bucket CSR -------------------------
        const int b  = blockIdx.x;
        const int n0 = b * 512;
        const int cnt   = bucket_cursor[b * CURPAD];
        const int ebase = b * CAP;
        const int gofs  = b * CAPC;

        sm.c.deg[t]       = (n0 + t       < N_NODES) ? 1 : 0;
        sm.c.deg[t + 256] = (n0 + t + 256 < N_NODES) ? 1 : 0;
        __syncthreads();

        for (int i = t; i < cnt; i += 256)
            atomicAdd(&sm.c.deg[eb[ebase + i] & 511], 1);
        __syncthreads();

        int d0 = sm.c.deg[2 * t], d1 = sm.c.deg[2 * t + 1];
        int ps = d0 + d1;
        sm.c.sdata[t] = ps;
        __syncthreads();
        for (int o = 1; o < 256; o <<= 1) {
            int add = (t >= o) ? sm.c.sdata[t - o] : 0;
            __syncthreads();
            sm.c.sdata[t] += add;
            __syncthreads();
        }
        int e0 = sm.c.sdata[t] - ps;
        int e1 = e0 + d0;
        __syncthreads();

        int na = n0 + 2 * t, nb2 = n0 + 2 * t + 1;
        if (na < N_NODES) {
            rowse[na] = make_int2(gofs + e0, gofs + e0 + d0);
            col[gofs + e0] = na;
        }
        if (nb2 < N_NODES) {
            rowse[nb2] = make_int2(gofs + e1, gofs + e1 + d1);
            col[gofs + e1] = nb2;
        }
        sm.c.deg[2 * t]     = e0 + 1;
        sm.c.deg[2 * t + 1] = e1 + 1;
        __syncthreads();

        for (int i = t; i < cnt; i += 256) {
            int v = eb[ebase + i];
            int r = atomicAdd(&sm.c.deg[v & 511], 1);
            col[gofs + r] = v >> BSH;
        }
    } else {
        // ------------------------------ GEMM ------------------------------
        const int r0 = (blockIdx.x - NB) * 64;

        for (int i = t; i < 2048; i += 256) {
            int row = i >> 5, kq = (i & 31) * 4;
            int gr = r0 + row;
            float4 v = make_float4(0.f, 0.f, 0.f, 0.f);
            if (gr < N_NODES) v = ((const float4*)(x + (size_t)gr * F_IN))[i & 31];
            short* p = &sm.g.xs[row * PADK + kq];
            p[0] = f2bs(v.x); p[1] = f2bs(v.y); p[2] = f2bs(v.z); p[3] = f2bs(v.w);
        }
        for (int i = t; i < 2048; i += 256) {
            int n = i >> 4, k0 = (i & 15) * 8;
            *(float4*)&sm.g.ws[n * PADK + k0] = *(const float4*)&wt[n * 128 + k0];
        }
        __syncthreads();

        const int wave = t >> 6, lane = t & 63;
        const int quad = lane >> 4, l16 = lane & 15;
        const int wrow = wave * 16;

        f32x4 acc[8];
        #pragma unroll
        for (int nt = 0; nt < 8; ++nt) acc[nt] = (f32x4){0.f, 0.f, 0.f, 0.f};

        const short* ap = &sm.g.xs[(wrow + l16) * PADK + quad * 8];
        #pragma unroll
        for (int kb = 0; kb < 4; ++kb) {
            short8 a = *(const short8*)(ap + kb * 32);
            #pragma unroll
            for (int nt = 0; nt < 8; ++nt) {
                short8 b = *(const short8*)&sm.g.ws[(nt * 16 + l16) * PADK + kb * 32 + quad * 8];
                acc[nt] = __builtin_amdgcn_mfma_f32_16x16x32_bf16(a, b, acc[nt], 0, 0, 0);
            }
        }

        float att_s[8], att_d[8];
        #pragma unroll
        for (int nt = 0; nt < 8; ++nt) {
            att_s[nt] = att_src[nt * 16 + l16];
            att_d[nt] = att_dst[nt * 16 + l16];
        }

        #pragma unroll
        for (int g = 0; g < 4; ++g) {
            int r = r0 + wrow + quad * 4 + g;
            if (r < N_NODES) {
                #pragma unroll
                for (int nt = 0; nt < 8; ++nt)
                    hb[(size_t)r * HC + nt * 16 + l16] = (unsigned short)f2bs(acc[nt][g]);
            }
            float s0 = acc[0][g] * att_s[0] + acc[1][g] * att_s[1];
            float s1 = acc[2][g] * att_s[2] + acc[3][g] * att_s[3];
            float s2 = acc[4][g] * att_s[4] + acc[5][g] * att_s[5];
            float s3 = acc[6][g] * att_s[6] + acc[7][g] * att_s[7];
            float d0 = acc[0][g] * att_d[0] + acc[1][g] * att_d[1];
            float d1 = acc[2][g] * att_d[2] + acc[3][g] * att_d[3];
            float d2 = acc[4][g] * att_d[4] + acc[5][g] * att_d[5];
            float d3 = acc[6][g] * att_d[6] + acc[7][g] * att_d[7];
            #pragma unroll
            for (int o = 1; o < 16; o <<= 1) {
                s0 += __shfl_xor(s0, o); s1 += __shfl_xor(s1, o);
                s2 += __shfl_xor(s2, o); s3 += __shfl_xor(s3, o);
                d0 += __shfl_xor(d0, o); d1 += __shfl_xor(d1, o);
                d2 += __shfl_xor(d2, o); d3 += __shfl_xor(d3, o);
            }
            if (l16 == 0 && r < N_NODES) {
                *(float4*)&a_src[r * NH] = make_float4(s0, s1, s2, s3);
                *(float4*)&a_dst[r * NH] = make_float4(d0, d1, d2, d3);
            }
        }
    }
}

// ---------------------------------------------------------------------------
// K3: per-dst-node softmax + aggregation, 4 edges per wave-iteration.
// Lane groups of 16 (g = lane>>4) each own one edge; each lane gathers a
// dwordx4 (16B) slice of the 256B hb row. Per 8 edges: 6 loads/lane (was 24),
// exp/leaky computed 4x per edge (was 16x). Epilogue: xor-16/32 group reduce,
// group 0 writes the out row as two f32x4 (ext-vector) NT stores.
// ---------------------------------------------------------------------------
__global__ __launch_bounds__(256) void k_node(const unsigned short* __restrict__ hb,
                                              const float* __restrict__ a_src,
                                              const float* __restrict__ a_dst,
                                              const int2* __restrict__ rowse,
                                              const int* __restrict__ col,
                                              const float* __restrict__ bias,
                                              float* __restrict__ out)
{
    const int lane = threadIdx.x & 63;
    const int node = blockIdx.x * 4 + (threadIdx.x >> 6);
    if (node >= N_NODES) return;

    const int g   = lane >> 4;   // edge slot within wave
    const int l16 = lane & 15;   // 16B slice within 256B row
    const int myh = l16 >> 2;    // head of my 8 elements

    const int2 se = rowse[node];
    const int r0 = se.x;
    const int cnt = se.y - se.x;

    const float adm = a_dst[node * NH + myh];

    float acc[8];
    #pragma unroll
    for (int k = 0; k < 8; ++k) acc[k] = 0.f;
    float denom = 0.f;

    int i = 0;
    for (; i + 8 <= cnt; i += 8) {
        int s0 = col[r0 + i + g];
        int s1 = col[r0 + i + 4 + g];
        float as0 = a_src[s0 * NH + myh];
        float as1 = a_src[s1 * NH + myh];
        uint4 h0 = ((const uint4*)(hb + (size_t)s0 * HC))[l16];
        uint4 h1 = ((const uint4*)(hb + (size_t)s1 * HC))[l16];
        float p0 = __expf(leaky(as0 + adm));
        float p1 = __expf(leaky(as1 + adm));
        denom += p0 + p1;
        acc[0] += p0 * __uint_as_float(h0.x << 16)        + p1 * __uint_as_float(h1.x << 16);
        acc[1] += p0 * __uint_as_float(h0.x & 0xffff0000u) + p1 * __uint_as_float(h1.x & 0xffff0000u);
        acc[2] += p0 * __uint_as_float(h0.y << 16)        + p1 * __uint_as_float(h1.y << 16);
        acc[3] += p0 * __uint_as_float(h0.y & 0xffff0000u) + p1 * __uint_as_float(h1.y & 0xffff0000u);
        acc[4] += p0 * __uint_as_float(h0.z << 16)        + p1 * __uint_as_float(h1.z << 16);
        acc[5] += p0 * __uint_as_float(h0.z & 0xffff0000u) + p1 * __uint_as_float(h1.z & 0xffff0000u);
        acc[6] += p0 * __uint_as_float(h0.w << 16)        + p1 * __uint_as_float(h1.w << 16);
        acc[7] += p0 * __uint_as_float(h0.w & 0xffff0000u) + p1 * __uint_as_float(h1.w & 0xffff0000u);
    }
    for (; i < cnt; i += 4) {
        int e = i + g;
        bool v = e < cnt;
        int s = col[r0 + (v ? e : 0)];
        float as = a_src[s * NH + myh];
        uint4 h0 = ((const uint4*)(hb + (size_t)s * HC))[l16];
        float p = v ? __expf(leaky(as + adm)) : 0.f;
        denom += p;
        acc[0] += p * __uint_as_float(h0.x << 16);
        acc[1] += p * __uint_as_float(h0.x & 0xffff0000u);
        acc[2] += p * __uint_as_float(h0.y << 16);
        acc[3] += p * __uint_as_float(h0.y & 0xffff0000u);
        acc[4] += p * __uint_as_float(h0.z << 16);
        acc[5] += p * __uint_as_float(h0.z & 0xffff0000u);
        acc[6] += p * __uint_as_float(h0.w << 16);
        acc[7] += p * __uint_as_float(h0.w & 0xffff0000u);
    }

    // reduce the 4 edge-groups: lanes l, l^16, l^32, l^48 hold the same slice
    #pragma unroll
    for (int o = 16; o < 64; o <<= 1) {
        denom += __shfl_xor(denom, o);
        #pragma unroll
        for (int k = 0; k < 8; ++k) acc[k] += __shfl_xor(acc[k], o);
    }

    if (g == 0) {
        float inv = 1.f / (denom + 1e-16f);
        const float* bp = &bias[l16 * 8];
        f32x4 o0, o1;
        o0.x = acc[0] * inv + bp[0]; o0.y = acc[1] * inv + bp[1];
        o0.z = acc[2] * inv + bp[2]; o0.w = acc[3] * inv + bp[3];
        o1.x = acc[4] * inv + bp[4]; o1.y = acc[5] * inv + bp[5];
        o1.z = acc[6] * inv + bp[6]; o1.w = acc[7] * inv + bp[7];
        __builtin_nontemporal_store(o0, (f32x4*)&out[(size_t)node * HC + l16 * 8]);
        __builtin_nontemporal_store(o1, (f32x4*)&out[(size_t)node * HC + l16 * 8 + 4]);
    }
}

// ---------------------------------------------------------------------------
extern "C" void kernel_launch(void* const* d_in, const int* in_sizes, int n_in,
                              void* d_out, int out_size, void* d_ws, size_t ws_size,
                              hipStream_t stream)
{
    const float* x       = (const float*)d_in[0];
    const float* W       = (const float*)d_in[1];
    const float* att_src = (const float*)d_in[2];
    const float* att_dst = (const float*)d_in[3];
    const float* bias    = (const float*)d_in[4];
    const int*   ei      = (const int*)d_in[5];
    const int E = in_sizes[5] / 2;
    const int* srcp = ei;
    const int* dstp = ei + E;
    float* out = (float*)d_out;

    char* wsb = (char*)d_ws;
    size_t off = 0;
    auto alloc = [&](size_t bytes) -> char* {
        char* p = wsb + off;
        off += (bytes + 255) & ~(size_t)255;
        return p;
    };
    unsigned short* hb = (unsigned short*)alloc((size_t)N_NODES * HC * sizeof(unsigned short)); // 25.6 MB
    float* a_src   = (float*)alloc((size_t)N_NODES * NH * sizeof(float));
    float* a_dst   = (float*)alloc((size_t)N_NODES * NH * sizeof(float));
    int*   eb      = (int*)alloc((size_t)NB * CAP * sizeof(int));          // 8.0 MB
    int*   col     = (int*)alloc((size_t)NB * CAPC * sizeof(int));         // 8.4 MB
    int2*  rowse   = (int2*)alloc((size_t)N_NODES * sizeof(int2));         // 0.8 MB
    int*   bcursor = (int*)alloc((size_t)NB * CURPAD * sizeof(int));       // 12.5 KB padded
    unsigned short* wt = (unsigned short*)alloc(128 * 128 * sizeof(unsigned short));

    const int bucketBlocks = (E + CHUNK - 1) / CHUNK;
    const int gemmBlocks   = (N_NODES + 63) / 64;

    k_pre<<<64, 256, 0, stream>>>(W, wt, bcursor);
    k_bucket<<<bucketBlocks, 256, 0, stream>>>(srcp, dstp, bcursor, eb, E);
    k_fused<<<NB + gemmBlocks, 256, 0, stream>>>(x, wt, att_src, att_dst,
                                                 hb, a_src, a_dst,
                                                 eb, bcursor, col, rowse);
    k_node<<<(N_NODES + 3) / 4, 256, 0, stream>>>(hb, a_src, a_dst, rowse, col, bias, out);
}

// Round 6
// 245.125 us; speedup vs baseline: 1.5553x; 1.0094x over previous
//
#include <hip/hip_runtime.h>
#include <hip/hip_bf16.h>
#include <math.h>

#define N_NODES 100000
#define F_IN    128
#define HC      128      // H*C
#define NH      4
#define SLOPE   0.2f

#define PADK    136      // LDS row stride in shorts (128 + 8 pad)

#define NB      196      // buckets = ceil(N/512)
#define BSH     9        // bucket = dst >> 9, local = dst & 511
#define CAP     10240    // per-bucket edge arena capacity (mean 8163, sigma ~90)
#define CAPC    10752    // per-bucket col arena (CAP + 512 self-loops)
#define CHUNK   2048     // edges per bucket block
#define CURPAD  16       // bucket_cursor stride in ints (64B: no false sharing)

typedef __attribute__((ext_vector_type(8))) short short8;   // bf16x8 MFMA frag
typedef __attribute__((ext_vector_type(4))) float f32x4;    // MFMA accum / native float4 (NT store ok)

static __device__ __forceinline__ float leaky(float x) { return x > 0.f ? x : SLOPE * x; }

static __device__ __forceinline__ short f2bs(float f) {
    __hip_bfloat16 b = __float2bfloat16(f);   // RTN-even
    return *reinterpret_cast<short*>(&b);
}

// ---------------------------------------------------------------------------
// K0: one-time W conversion W[k][n] fp32 -> wt[n][k] bf16, AND zero the
// bucket cursors (replaces the hipMemsetAsync dispatch).
// ---------------------------------------------------------------------------
__global__ __launch_bounds__(256) void k_pre(const float* __restrict__ W,
                                             unsigned short* __restrict__ wt,
                                             int* __restrict__ bucket_cursor)
{
    int t = blockIdx.x * 256 + threadIdx.x;
    if (t < 128 * 128) {
        int k = t >> 7, n = t & 127;
        wt[n * 128 + k] = (unsigned short)f2bs(W[k * HC + n]);
    }
    if (t < NB * CURPAD) bucket_cursor[t] = 0;
}

// ---------------------------------------------------------------------------
// K1 (fused): blocks [0, bucketBlocks) = edge multisplit (latency-bound,
// hides under gemm); blocks [bucketBlocks, +1563) = GEMM (round-3 topology,
// which measured best). Bucket half caches (src,dst) in registers so the
// edge list is read ONCE (was twice).
// LDS union: gemm 52.2 KB, bucket 14.3 KB -> 3 blocks/CU either way.
// ---------------------------------------------------------------------------
union SMem {
    struct {
        short xs[64 * PADK];     // bf16 x tile [row][k]   17.4 KB
        short ws[128 * PADK];    // bf16 W^T    [n][k]     34.8 KB
    } g;
    struct {
        int ebuf[CHUNK];
        unsigned char bkt[CHUNK];
        int hist[256];
        int lexcl[257];
        int gbase[256];
        int sdata[256];
    } b;
};

__global__ __launch_bounds__(256) void k_main(const float* __restrict__ x,
                                              const unsigned short* __restrict__ wt,
                                              const float* __restrict__ att_src,
                                              const float* __restrict__ att_dst,
                                              unsigned short* __restrict__ hb,
                                              float* __restrict__ a_src,
                                              float* __restrict__ a_dst,
                                              const int* __restrict__ srcp,
                                              const int* __restrict__ dstp,
                                              int* __restrict__ bucket_cursor,
                                              int* __restrict__ eb, int E,
                                              int bucketBlocks)
{
    __shared__ SMem sm;
    const int t = threadIdx.x;

    if ((int)blockIdx.x < bucketBlocks) {
        // ---------------------------- multisplit --------------------------
        const int base = blockIdx.x * CHUNK;

        sm.b.hist[t] = 0;
        __syncthreads();

        int sreg[8], dreg[8];
        #pragma unroll
        for (int j = 0; j < CHUNK / 256; ++j) {
            int i = base + t + j * 256;
            bool v = i < E;
            sreg[j] = v ? srcp[i] : 0;
            dreg[j] = v ? dstp[i] : -1;
            if (v) atomicAdd(&sm.b.hist[dreg[j] >> BSH], 1);
        }
        __syncthreads();

        int cnt = sm.b.hist[t];
        sm.b.sdata[t] = cnt;
        __syncthreads();
        for (int o = 1; o < 256; o <<= 1) {
            int add = (t >= o) ? sm.b.sdata[t - o] : 0;
            __syncthreads();
            sm.b.sdata[t] += add;
            __syncthreads();
        }
        int excl = sm.b.sdata[t] - cnt;
        sm.b.lexcl[t] = excl;
        if (t == 255) sm.b.lexcl[256] = sm.b.sdata[255];
        sm.b.hist[t] = excl;
        int gb = 0;
        if (t < NB && cnt > 0) gb = atomicAdd(&bucket_cursor[t * CURPAD], cnt);
        sm.b.gbase[t] = t * CAP + gb;
        __syncthreads();

        #pragma unroll
        for (int j = 0; j < CHUNK / 256; ++j) {
            if (dreg[j] >= 0) {
                int b = dreg[j] >> BSH;
                int r = atomicAdd(&sm.b.hist[b], 1);
                sm.b.ebuf[r] = (sreg[j] << BSH) | (dreg[j] & 511);
                sm.b.bkt[r] = (unsigned char)b;
            }
        }
        __syncthreads();

        const int blockTotal = sm.b.lexcl[256];
        for (int i = t; i < blockTotal; i += 256) {
            int b = sm.b.bkt[i];
            eb[sm.b.gbase[b] + (i - sm.b.lexcl[b])] = sm.b.ebuf[i];
        }
    } else {
        // ------------------------------ GEMM ------------------------------
        const int r0 = (blockIdx.x - bucketBlocks) * 64;

        for (int i = t; i < 2048; i += 256) {
            int row = i >> 5, kq = (i & 31) * 4;
            int gr = r0 + row;
            float4 v = make_float4(0.f, 0.f, 0.f, 0.f);
            if (gr < N_NODES) v = ((const float4*)(x + (size_t)gr * F_IN))[i & 31];
            short* p = &sm.g.xs[row * PADK + kq];
            p[0] = f2bs(v.x); p[1] = f2bs(v.y); p[2] = f2bs(v.z); p[3] = f2bs(v.w);
        }
        for (int i = t; i < 2048; i += 256) {
            int n = i >> 4, k0 = (i & 15) * 8;
            *(float4*)&sm.g.ws[n * PADK + k0] = *(const float4*)&wt[n * 128 + k0];
        }
        __syncthreads();

        const int wave = t >> 6, lane = t & 63;
        const int quad = lane >> 4, l16 = lane & 15;
        const int wrow = wave * 16;

        f32x4 acc[8];
        #pragma unroll
        for (int nt = 0; nt < 8; ++nt) acc[nt] = (f32x4){0.f, 0.f, 0.f, 0.f};

        const short* ap = &sm.g.xs[(wrow + l16) * PADK + quad * 8];
        #pragma unroll
        for (int kb = 0; kb < 4; ++kb) {
            short8 a = *(const short8*)(ap + kb * 32);
            #pragma unroll
            for (int nt = 0; nt < 8; ++nt) {
                short8 b = *(const short8*)&sm.g.ws[(nt * 16 + l16) * PADK + kb * 32 + quad * 8];
                acc[nt] = __builtin_amdgcn_mfma_f32_16x16x32_bf16(a, b, acc[nt], 0, 0, 0);
            }
        }

        float att_s[8], att_d[8];
        #pragma unroll
        for (int nt = 0; nt < 8; ++nt) {
            att_s[nt] = att_src[nt * 16 + l16];
            att_d[nt] = att_dst[nt * 16 + l16];
        }

        #pragma unroll
        for (int g = 0; g < 4; ++g) {
            int r = r0 + wrow + quad * 4 + g;
            if (r < N_NODES) {
                #pragma unroll
                for (int nt = 0; nt < 8; ++nt)
                    hb[(size_t)r * HC + nt * 16 + l16] = (unsigned short)f2bs(acc[nt][g]);
            }
            float s0 = acc[0][g] * att_s[0] + acc[1][g] * att_s[1];
            float s1 = acc[2][g] * att_s[2] + acc[3][g] * att_s[3];
            float s2 = acc[4][g] * att_s[4] + acc[5][g] * att_s[5];
            float s3 = acc[6][g] * att_s[6] + acc[7][g] * att_s[7];
            float d0 = acc[0][g] * att_d[0] + acc[1][g] * att_d[1];
            float d1 = acc[2][g] * att_d[2] + acc[3][g] * att_d[3];
            float d2 = acc[4][g] * att_d[4] + acc[5][g] * att_d[5];
            float d3 = acc[6][g] * att_d[6] + acc[7][g] * att_d[7];
            #pragma unroll
            for (int o = 1; o < 16; o <<= 1) {
                s0 += __shfl_xor(s0, o); s1 += __shfl_xor(s1, o);
                s2 += __shfl_xor(s2, o); s3 += __shfl_xor(s3, o);
                d0 += __shfl_xor(d0, o); d1 += __shfl_xor(d1, o);
                d2 += __shfl_xor(d2, o); d3 += __shfl_xor(d3, o);
            }
            if (l16 == 0 && r < N_NODES) {
                *(float4*)&a_src[r * NH] = make_float4(s0, s1, s2, s3);
                *(float4*)&a_dst[r * NH] = make_float4(d0, d1, d2, d3);
            }
        }
    }
}

// ---------------------------------------------------------------------------
// K2: per-bucket CSR build, 1024 threads/block, fixed per-bucket col arena
// (gofs = b*CAPC). Self-loop at slot 0.
// ---------------------------------------------------------------------------
__global__ __launch_bounds__(1024) void k_csr(const int* __restrict__ eb,
                                              const int* __restrict__ bucket_cursor,
                                              int* __restrict__ col,
                                              int2* __restrict__ rowse)
{
    __shared__ int deg[512];
    __shared__ int sdata[256];

    const int t  = threadIdx.x;
    const int b  = blockIdx.x;
    const int n0 = b * 512;
    const int cnt   = bucket_cursor[b * CURPAD];
    const int ebase = b * CAP;
    const int gofs  = b * CAPC;

    if (t < 512) deg[t] = (n0 + t < N_NODES) ? 1 : 0;
    __syncthreads();

    for (int i = t; i < cnt; i += 1024)
        atomicAdd(&deg[eb[ebase + i] & 511], 1);
    __syncthreads();

    int d0 = 0, d1 = 0, ps = 0;
    if (t < 256) {
        d0 = deg[2 * t]; d1 = deg[2 * t + 1];
        ps = d0 + d1;
        sdata[t] = ps;
    }
    __syncthreads();
    for (int o = 1; o < 256; o <<= 1) {
        int add = 0;
        if (t < 256 && t >= o) add = sdata[t - o];
        __syncthreads();
        if (t < 256) sdata[t] += add;
        __syncthreads();
    }
    if (t < 256) {
        int e0 = sdata[t] - ps;
        int e1 = e0 + d0;
        int na = n0 + 2 * t, nb2 = n0 + 2 * t + 1;
        if (na < N_NODES) {
            rowse[na] = make_int2(gofs + e0, gofs + e0 + d0);
            col[gofs + e0] = na;
        }
        if (nb2 < N_NODES) {
            rowse[nb2] = make_int2(gofs + e1, gofs + e1 + d1);
            col[gofs + e1] = nb2;
        }
        deg[2 * t]     = e0 + 1;
        deg[2 * t + 1] = e1 + 1;
    }
    __syncthreads();

    for (int i = t; i < cnt; i += 1024) {
        int v = eb[ebase + i];
        int r = atomicAdd(&deg[v & 511], 1);
        col[gofs + r] = v >> BSH;
    }
}

// ---------------------------------------------------------------------------
// K3: per-dst-node softmax + aggregation, 16-lane groups own edges, 3-deep
// software pipeline: col indices fetched 2 iters ahead, a_src/hb gathers
// issued 1 iter ahead, compute consumes previous stage. All pipeline guards
// are wave-uniform (cnt is per-wave) -> no divergence. Masked edges clamp
// to col[r0] (self-loop, always valid) with p forced to 0.
// ---------------------------------------------------------------------------
__global__ __launch_bounds__(256) void k_node(const unsigned short* __restrict__ hb,
                                              const float* __restrict__ a_src,
                                              const float* __restrict__ a_dst,
                                              const int2* __restrict__ rowse,
                                              const int* __restrict__ col,
                                              const float* __restrict__ bias,
                                              float* __restrict__ out)
{
    const int lane = threadIdx.x & 63;
    const int node = blockIdx.x * 4 + (threadIdx.x >> 6);
    if (node >= N_NODES) return;

    const int g   = lane >> 4;   // edge slot within wave
    const int l16 = lane & 15;   // 16B slice within 256B row
    const int myh = l16 >> 2;    // head of my 8 elements

    const int2 se = rowse[node];
    const int r0 = se.x;
    const int cnt = se.y - se.x;

    const float adm = a_dst[node * NH + myh];

    float acc[8];
    #pragma unroll
    for (int k = 0; k < 8; ++k) acc[k] = 0.f;
    float denom = 0.f;

    // pipeline state
    bool vA0, vA1, vB0, vB1;
    int  cB0, cB1;
    float aA0, aA1;
    uint4 hA0, hA1;

    {   // cols + gathers for iter 0
        int e0 = g, e1 = 4 + g;
        vA0 = e0 < cnt; vA1 = e1 < cnt;
        int c0 = col[r0 + (vA0 ? e0 : 0)];
        int c1 = col[r0 + (vA1 ? e1 : 0)];
        aA0 = a_src[c0 * NH + myh];
        aA1 = a_src[c1 * NH + myh];
        hA0 = ((const uint4*)(hb + (size_t)c0 * HC))[l16];
        hA1 = ((const uint4*)(hb + (size_t)c1 * HC))[l16];
    }
    {   // cols for iter 1
        int e0 = 8 + g, e1 = 12 + g;
        vB0 = e0 < cnt; vB1 = e1 < cnt;
        cB0 = col[r0 + (vB0 ? e0 : 0)];
        cB1 = col[r0 + (vB1 ? e1 : 0)];
    }

    for (int i = 0; i < cnt; i += 8) {
        const bool more = (i + 8 < cnt);        // wave-uniform
        float aN0 = 0.f, aN1 = 0.f;
        uint4 hN0 = make_uint4(0, 0, 0, 0), hN1 = make_uint4(0, 0, 0, 0);
        int cC0 = 0, cC1 = 0;
        bool vC0 = false, vC1 = false;
        if (more) {
            // gathers for iter i+8
            aN0 = a_src[cB0 * NH + myh];
            aN1 = a_src[cB1 * NH + myh];
            hN0 = ((const uint4*)(hb + (size_t)cB0 * HC))[l16];
            hN1 = ((const uint4*)(hb + (size_t)cB1 * HC))[l16];
            // cols for iter i+16
            int e0 = i + 16 + g, e1 = i + 20 + g;
            vC0 = e0 < cnt; vC1 = e1 < cnt;
            cC0 = col[r0 + (vC0 ? e0 : 0)];
            cC1 = col[r0 + (vC1 ? e1 : 0)];
        }
        // compute iter i
        float p0 = vA0 ? __expf(leaky(aA0 + adm)) : 0.f;
        float p1 = vA1 ? __expf(leaky(aA1 + adm)) : 0.f;
        denom += p0 + p1;
        acc[0] += p0 * __uint_as_float(hA0.x << 16)         + p1 * __uint_as_float(hA1.x << 16);
        acc[1] += p0 * __uint_as_float(hA0.x & 0xffff0000u) + p1 * __uint_as_float(hA1.x & 0xffff0000u);
        acc[2] += p0 * __uint_as_float(hA0.y << 16)         + p1 * __uint_as_float(hA1.y << 16);
        acc[3] += p0 * __uint_as_float(hA0.y & 0xffff0000u) + p1 * __uint_as_float(hA1.y & 0xffff0000u);
        acc[4] += p0 * __uint_as_float(hA0.z << 16)         + p1 * __uint_as_float(hA1.z << 16);
        acc[5] += p0 * __uint_as_float(hA0.z & 0xffff0000u) + p1 * __uint_as_float(hA1.z & 0xffff0000u);
        acc[6] += p0 * __uint_as_float(hA0.w << 16)         + p1 * __uint_as_float(hA1.w << 16);
        acc[7] += p0 * __uint_as_float(hA0.w & 0xffff0000u) + p1 * __uint_as_float(hA1.w & 0xffff0000u);
        if (more) {
            vA0 = vB0; vA1 = vB1;
            aA0 = aN0; aA1 = aN1; hA0 = hN0; hA1 = hN1;
            vB0 = vC0; vB1 = vC1; cB0 = cC0; cB1 = cC1;
        }
    }

    // reduce the 4 edge-groups: lanes l, l^16, l^32, l^48 hold the same slice
    #pragma unroll
    for (int o = 16; o < 64; o <<= 1) {
        denom += __shfl_xor(denom, o);
        #pragma unroll
        for (int k = 0; k < 8; ++k) acc[k] += __shfl_xor(acc[k], o);
    }

    if (g == 0) {
        float inv = 1.f / (denom + 1e-16f);
        const float* bp = &bias[l16 * 8];
        f32x4 o0, o1;
        o0.x = acc[0] * inv + bp[0]; o0.y = acc[1] * inv + bp[1];
        o0.z = acc[2] * inv + bp[2]; o0.w = acc[3] * inv + bp[3];
        o1.x = acc[4] * inv + bp[4]; o1.y = acc[5] * inv + bp[5];
        o1.z = acc[6] * inv + bp[6]; o1.w = acc[7] * inv + bp[7];
        __builtin_nontemporal_store(o0, (f32x4*)&out[(size_t)node * HC + l16 * 8]);
        __builtin_nontemporal_store(o1, (f32x4*)&out[(size_t)node * HC + l16 * 8 + 4]);
    }
}

// ---------------------------------------------------------------------------
extern "C" void kernel_launch(void* const* d_in, const int* in_sizes, int n_in,
                              void* d_out, int out_size, void* d_ws, size_t ws_size,
                              hipStream_t stream)
{
    const float* x       = (const float*)d_in[0];
    const float* W       = (const float*)d_in[1];
    const float* att_src = (const float*)d_in[2];
    const float* att_dst = (const float*)d_in[3];
    const float* bias    = (const float*)d_in[4];
    const int*   ei      = (const int*)d_in[5];
    const int E = in_sizes[5] / 2;
    const int* srcp = ei;
    const int* dstp = ei + E;
    float* out = (float*)d_out;

    char* wsb = (char*)d_ws;
    size_t off = 0;
    auto alloc = [&](size_t bytes) -> char* {
        char* p = wsb + off;
        off += (bytes + 255) & ~(size_t)255;
        return p;
    };
    unsigned short* hb = (unsigned short*)alloc((size_t)N_NODES * HC * sizeof(unsigned short)); // 25.6 MB
    float* a_src   = (float*)alloc((size_t)N_NODES * NH * sizeof(float));
    float* a_dst   = (float*)alloc((size_t)N_NODES * NH * sizeof(float));
    int*   eb      = (int*)alloc((size_t)NB * CAP * sizeof(int));          // 8.0 MB
    int*   col     = (int*)alloc((size_t)NB * CAPC * sizeof(int));         // 8.4 MB
    int2*  rowse   = (int2*)alloc((size_t)N_NODES * sizeof(int2));         // 0.8 MB
    int*   bcursor = (int*)alloc((size_t)NB * CURPAD * sizeof(int));       // 12.5 KB padded
    unsigned short* wt = (unsigned short*)alloc(128 * 128 * sizeof(unsigned short));

    const int bucketBlocks = (E + CHUNK - 1) / CHUNK;
    const int gemmBlocks   = (N_NODES + 63) / 64;

    k_pre<<<64, 256, 0, stream>>>(W, wt, bcursor);
    k_main<<<bucketBlocks + gemmBlocks, 256, 0, stream>>>(x, wt, att_src, att_dst,
                                                          hb, a_src, a_dst,
                                                          srcp, dstp, bcursor, eb, E,
                                                          bucketBlocks);
    k_csr<<<NB, 1024, 0, stream>>>(eb, bcursor, col, rowse);
    k_node<<<(N_NODES + 3) / 4, 256, 0, stream>>>(hb, a_src, a_dst, rowse, col, bias, out);
}

// Round 7
// 244.396 us; speedup vs baseline: 1.5599x; 1.0030x over previous
//
#include <hip/hip_runtime.h>
#include <hip/hip_bf16.h>
#include <math.h>

#define N_NODES 100000
#define F_IN    128
#define HC      128      // H*C
#define NH      4
#define SLOPE   0.2f

#define PADK    136      // LDS row stride in shorts (128 + 8 pad)

#define NB      196      // buckets = ceil(N/512)
#define BSH     9        // bucket = dst >> 9, local = dst & 511
#define CAP     10240    // per-bucket edge arena capacity (mean 8163, sigma ~90)
#define CAPC    10752    // per-bucket col arena (CAP + 512 self-loops); tail zero-filled
#define CHUNK   2048     // edges per bucket block
#define CURPAD  16       // bucket_cursor stride in ints (64B: no false sharing)

typedef __attribute__((ext_vector_type(8))) short short8;   // bf16x8 MFMA frag
typedef __attribute__((ext_vector_type(4))) float f32x4;    // MFMA accum / native float4 (NT store ok)
typedef __attribute__((ext_vector_type(2))) float fx2;      // float2 for v_pk_fma_f32

static __device__ __forceinline__ float leaky(float x) { return x > 0.f ? x : SLOPE * x; }

static __device__ __forceinline__ short f2bs(float f) {
    __hip_bfloat16 b = __float2bfloat16(f);   // RTN-even
    return *reinterpret_cast<short*>(&b);
}

// unpack a bf16 pair (one u32) into a float2: lo -> .x, hi -> .y
static __device__ __forceinline__ fx2 bf2f2(unsigned int v) {
    fx2 r;
    r.x = __uint_as_float(v << 16);
    r.y = __uint_as_float(v & 0xffff0000u);
    return r;
}

// ---------------------------------------------------------------------------
// K0: one-time W conversion W[k][n] fp32 -> wt[n][k] bf16, AND zero the
// bucket cursors (replaces the hipMemsetAsync dispatch).
// ---------------------------------------------------------------------------
__global__ __launch_bounds__(256) void k_pre(const float* __restrict__ W,
                                             unsigned short* __restrict__ wt,
                                             int* __restrict__ bucket_cursor)
{
    int t = blockIdx.x * 256 + threadIdx.x;
    if (t < 128 * 128) {
        int k = t >> 7, n = t & 127;
        wt[n * 128 + k] = (unsigned short)f2bs(W[k * HC + n]);
    }
    if (t < NB * CURPAD) bucket_cursor[t] = 0;
}

// ---------------------------------------------------------------------------
// K1 (fused): blocks [0, bucketBlocks) = edge multisplit (latency-bound,
// hides under gemm); blocks [bucketBlocks, +1563) = GEMM. Bucket half caches
// (src,dst) in registers so the edge list is read ONCE.
// LDS union: gemm 52.2 KB, bucket 14.3 KB -> 3 blocks/CU either way.
// ---------------------------------------------------------------------------
union SMem {
    struct {
        short xs[64 * PADK];     // bf16 x tile [row][k]   17.4 KB
        short ws[128 * PADK];    // bf16 W^T    [n][k]     34.8 KB
    } g;
    struct {
        int ebuf[CHUNK];
        unsigned char bkt[CHUNK];
        int hist[256];
        int lexcl[257];
        int gbase[256];
        int sdata[256];
    } b;
};

__global__ __launch_bounds__(256) void k_main(const float* __restrict__ x,
                                              const unsigned short* __restrict__ wt,
                                              const float* __restrict__ att_src,
                                              const float* __restrict__ att_dst,
                                              unsigned short* __restrict__ hb,
                                              float* __restrict__ a_src,
                                              float* __restrict__ a_dst,
                                              const int* __restrict__ srcp,
                                              const int* __restrict__ dstp,
                                              int* __restrict__ bucket_cursor,
                                              int* __restrict__ eb, int E,
                                              int bucketBlocks)
{
    __shared__ SMem sm;
    const int t = threadIdx.x;

    if ((int)blockIdx.x < bucketBlocks) {
        // ---------------------------- multisplit --------------------------
        const int base = blockIdx.x * CHUNK;

        sm.b.hist[t] = 0;
        __syncthreads();

        int sreg[8], dreg[8];
        #pragma unroll
        for (int j = 0; j < CHUNK / 256; ++j) {
            int i = base + t + j * 256;
            bool v = i < E;
            sreg[j] = v ? srcp[i] : 0;
            dreg[j] = v ? dstp[i] : -1;
            if (v) atomicAdd(&sm.b.hist[dreg[j] >> BSH], 1);
        }
        __syncthreads();

        int cnt = sm.b.hist[t];
        sm.b.sdata[t] = cnt;
        __syncthreads();
        for (int o = 1; o < 256; o <<= 1) {
            int add = (t >= o) ? sm.b.sdata[t - o] : 0;
            __syncthreads();
            sm.b.sdata[t] += add;
            __syncthreads();
        }
        int excl = sm.b.sdata[t] - cnt;
        sm.b.lexcl[t] = excl;
        if (t == 255) sm.b.lexcl[256] = sm.b.sdata[255];
        sm.b.hist[t] = excl;
        int gb = 0;
        if (t < NB && cnt > 0) gb = atomicAdd(&bucket_cursor[t * CURPAD], cnt);
        sm.b.gbase[t] = t * CAP + gb;
        __syncthreads();

        #pragma unroll
        for (int j = 0; j < CHUNK / 256; ++j) {
            if (dreg[j] >= 0) {
                int b = dreg[j] >> BSH;
                int r = atomicAdd(&sm.b.hist[b], 1);
                sm.b.ebuf[r] = (sreg[j] << BSH) | (dreg[j] & 511);
                sm.b.bkt[r] = (unsigned char)b;
            }
        }
        __syncthreads();

        const int blockTotal = sm.b.lexcl[256];
        for (int i = t; i < blockTotal; i += 256) {
            int b = sm.b.bkt[i];
            eb[sm.b.gbase[b] + (i - sm.b.lexcl[b])] = sm.b.ebuf[i];
        }
    } else {
        // ------------------------------ GEMM ------------------------------
        const int r0 = (blockIdx.x - bucketBlocks) * 64;

        for (int i = t; i < 2048; i += 256) {
            int row = i >> 5, kq = (i & 31) * 4;
            int gr = r0 + row;
            float4 v = make_float4(0.f, 0.f, 0.f, 0.f);
            if (gr < N_NODES) v = ((const float4*)(x + (size_t)gr * F_IN))[i & 31];
            short* p = &sm.g.xs[row * PADK + kq];
            p[0] = f2bs(v.x); p[1] = f2bs(v.y); p[2] = f2bs(v.z); p[3] = f2bs(v.w);
        }
        for (int i = t; i < 2048; i += 256) {
            int n = i >> 4, k0 = (i & 15) * 8;
            *(float4*)&sm.g.ws[n * PADK + k0] = *(const float4*)&wt[n * 128 + k0];
        }
        __syncthreads();

        const int wave = t >> 6, lane = t & 63;
        const int quad = lane >> 4, l16 = lane & 15;
        const int wrow = wave * 16;

        f32x4 acc[8];
        #pragma unroll
        for (int nt = 0; nt < 8; ++nt) acc[nt] = (f32x4){0.f, 0.f, 0.f, 0.f};

        const short* ap = &sm.g.xs[(wrow + l16) * PADK + quad * 8];
        #pragma unroll
        for (int kb = 0; kb < 4; ++kb) {
            short8 a = *(const short8*)(ap + kb * 32);
            #pragma unroll
            for (int nt = 0; nt < 8; ++nt) {
                short8 b = *(const short8*)&sm.g.ws[(nt * 16 + l16) * PADK + kb * 32 + quad * 8];
                acc[nt] = __builtin_amdgcn_mfma_f32_16x16x32_bf16(a, b, acc[nt], 0, 0, 0);
            }
        }

        float att_s[8], att_d[8];
        #pragma unroll
        for (int nt = 0; nt < 8; ++nt) {
            att_s[nt] = att_src[nt * 16 + l16];
            att_d[nt] = att_dst[nt * 16 + l16];
        }

        #pragma unroll
        for (int g = 0; g < 4; ++g) {
            int r = r0 + wrow + quad * 4 + g;
            if (r < N_NODES) {
                #pragma unroll
                for (int nt = 0; nt < 8; ++nt)
                    hb[(size_t)r * HC + nt * 16 + l16] = (unsigned short)f2bs(acc[nt][g]);
            }
            float s0 = acc[0][g] * att_s[0] + acc[1][g] * att_s[1];
            float s1 = acc[2][g] * att_s[2] + acc[3][g] * att_s[3];
            float s2 = acc[4][g] * att_s[4] + acc[5][g] * att_s[5];
            float s3 = acc[6][g] * att_s[6] + acc[7][g] * att_s[7];
            float d0 = acc[0][g] * att_d[0] + acc[1][g] * att_d[1];
            float d1 = acc[2][g] * att_d[2] + acc[3][g] * att_d[3];
            float d2 = acc[4][g] * att_d[4] + acc[5][g] * att_d[5];
            float d3 = acc[6][g] * att_d[6] + acc[7][g] * att_d[7];
            #pragma unroll
            for (int o = 1; o < 16; o <<= 1) {
                s0 += __shfl_xor(s0, o); s1 += __shfl_xor(s1, o);
                s2 += __shfl_xor(s2, o); s3 += __shfl_xor(s3, o);
                d0 += __shfl_xor(d0, o); d1 += __shfl_xor(d1, o);
                d2 += __shfl_xor(d2, o); d3 += __shfl_xor(d3, o);
            }
            if (l16 == 0 && r < N_NODES) {
                *(float4*)&a_src[r * NH] = make_float4(s0, s1, s2, s3);
                *(float4*)&a_dst[r * NH] = make_float4(d0, d1, d2, d3);
            }
        }
    }
}

// ---------------------------------------------------------------------------
// K2: per-bucket CSR build, 1024 threads/block. col staged in LDS (scatter
// hits LDS, not random global), tail [cnt+512, CAPC) zero-filled (enables
// k_node's guard-free prefetch), then ONE coalesced int4 flush to global.
// Self-loop at slot 0 of each node.
// ---------------------------------------------------------------------------
__global__ __launch_bounds__(1024) void k_csr(const int* __restrict__ eb,
                                              const int* __restrict__ bucket_cursor,
                                              int* __restrict__ col,
                                              int2* __restrict__ rowse)
{
    __shared__ int deg[512];
    __shared__ int sdata[256];
    __shared__ alignas(16) int colL[CAPC];   // 43 KB

    const int t  = threadIdx.x;
    const int b  = blockIdx.x;
    const int n0 = b * 512;
    const int cnt   = bucket_cursor[b * CURPAD];
    const int ebase = b * CAP;
    const int gofs  = b * CAPC;
    const int nvalid = min(512, N_NODES - n0);
    const int top = cnt + nvalid;            // used entries in this arena

    if (t < 512) deg[t] = (t < nvalid) ? 1 : 0;
    __syncthreads();

    for (int i = t; i < cnt; i += 1024)
        atomicAdd(&deg[eb[ebase + i] & 511], 1);
    __syncthreads();

    int d0 = 0, d1 = 0, ps = 0;
    if (t < 256) {
        d0 = deg[2 * t]; d1 = deg[2 * t + 1];
        ps = d0 + d1;
        sdata[t] = ps;
    }
    __syncthreads();
    for (int o = 1; o < 256; o <<= 1) {
        int add = 0;
        if (t < 256 && t >= o) add = sdata[t - o];
        __syncthreads();
        if (t < 256) sdata[t] += add;
        __syncthreads();
    }
    if (t < 256) {
        int e0 = sdata[t] - ps;
        int e1 = e0 + d0;
        int na = n0 + 2 * t, nb2 = n0 + 2 * t + 1;
        if (na < N_NODES) {
            rowse[na] = make_int2(gofs + e0, gofs + e0 + d0);
            colL[e0] = na;
        }
        if (nb2 < N_NODES) {
            rowse[nb2] = make_int2(gofs + e1, gofs + e1 + d1);
            colL[e1] = nb2;
        }
        deg[2 * t]     = e0 + 1;
        deg[2 * t + 1] = e1 + 1;
    }
    __syncthreads();

    for (int i = t; i < cnt; i += 1024) {
        int v = eb[ebase + i];
        int r = atomicAdd(&deg[v & 511], 1);
        colL[r] = v >> BSH;
    }
    // zero the tail so k_node can prefetch past the end safely
    for (int i = top + t; i < CAPC; i += 1024) colL[i] = 0;
    __syncthreads();

    // coalesced flush: 16B per lane
    const int4* s4 = (const int4*)colL;
    int4* d4 = (int4*)(col + gofs);
    for (int i = t; i < CAPC / 4; i += 1024) d4[i] = s4[i];
}

// ---------------------------------------------------------------------------
// K3: per-dst-node softmax + aggregation. 16-lane groups own edges; 3-deep
// GUARD-FREE software pipeline: the col arena tail is zero-filled, so all
// read-ahead indices (<= top+22 < CAPC) land on valid packed entries or
// zeros -> no validity flags on addresses; only the final p is masked.
// Packed float2 FMAs (v_pk_fma_f32) halve the accumulate issue count.
// ---------------------------------------------------------------------------
__global__ __launch_bounds__(256) void k_node(const unsigned short* __restrict__ hb,
                                              const float* __restrict__ a_src,
                                              const float* __restrict__ a_dst,
                                              const int2* __restrict__ rowse,
                                              const int* __restrict__ col,
                                              const float* __restrict__ bias,
                                              float* __restrict__ out)
{
    const int lane = threadIdx.x & 63;
    const int node = blockIdx.x * 4 + (threadIdx.x >> 6);
    if (node >= N_NODES) return;

    const int g   = lane >> 4;   // edge slot within wave
    const int l16 = lane & 15;   // 16B slice within 256B row
    const int myh = l16 >> 2;    // head of my 8 elements

    const int2 se = rowse[node];
    const int r0 = se.x;
    const int cnt = se.y - se.x;

    const float adm = a_dst[node * NH + myh];

    fx2 acc2[4];
    #pragma unroll
    for (int k = 0; k < 4; ++k) acc2[k] = (fx2){0.f, 0.f};
    float denom = 0.f;

    // pipeline prologue (all loads unconditionally safe within the arena)
    int   cA0 = col[r0 + g];
    int   cA1 = col[r0 + 4 + g];
    float aA0 = a_src[cA0 * NH + myh];
    float aA1 = a_src[cA1 * NH + myh];
    uint4 hA0 = ((const uint4*)(hb + (size_t)cA0 * HC))[l16];
    uint4 hA1 = ((const uint4*)(hb + (size_t)cA1 * HC))[l16];
    int   cB0 = col[r0 + 8 + g];
    int   cB1 = col[r0 + 12 + g];

    for (int i = 0; i < cnt; i += 8) {
        // gathers for iter i+8 (indices from zero-tail are node 0 -> valid)
        float aN0 = a_src[cB0 * NH + myh];
        float aN1 = a_src[cB1 * NH + myh];
        uint4 hN0 = ((const uint4*)(hb + (size_t)cB0 * HC))[l16];
        uint4 hN1 = ((const uint4*)(hb + (size_t)cB1 * HC))[l16];
        // cols for iter i+16 (max index top+22 < CAPC: zero-filled, safe)
        int cC0 = col[r0 + i + 16 + g];
        int cC1 = col[r0 + i + 20 + g];

        // compute iter i: only p is masked
        float p0 = (i + g     < cnt) ? __expf(leaky(aA0 + adm)) : 0.f;
        float p1 = (i + 4 + g < cnt) ? __expf(leaky(aA1 + adm)) : 0.f;
        denom += p0 + p1;
        fx2 pb0 = (fx2){p0, p0}, pb1 = (fx2){p1, p1};
        acc2[0] = __builtin_elementwise_fma(bf2f2(hA0.x), pb0, acc2[0]);
        acc2[0] = __builtin_elementwise_fma(bf2f2(hA1.x), pb1, acc2[0]);
        acc2[1] = __builtin_elementwise_fma(bf2f2(hA0.y), pb0, acc2[1]);
        acc2[1] = __builtin_elementwise_fma(bf2f2(hA1.y), pb1, acc2[1]);
        acc2[2] = __builtin_elementwise_fma(bf2f2(hA0.z), pb0, acc2[2]);
        acc2[2] = __builtin_elementwise_fma(bf2f2(hA1.z), pb1, acc2[2]);
        acc2[3] = __builtin_elementwise_fma(bf2f2(hA0.w), pb0, acc2[3]);
        acc2[3] = __builtin_elementwise_fma(bf2f2(hA1.w), pb1, acc2[3]);

        // rotate pipeline
        aA0 = aN0; aA1 = aN1; hA0 = hN0; hA1 = hN1;
        cB0 = cC0; cB1 = cC1;
    }

    // reduce the 4 edge-groups: lanes l, l^16, l^32, l^48 hold the same slice
    #pragma unroll
    for (int o = 16; o < 64; o <<= 1) {
        denom += __shfl_xor(denom, o);
        #pragma unroll
        for (int k = 0; k < 4; ++k) {
            acc2[k].x += __shfl_xor(acc2[k].x, o);
            acc2[k].y += __shfl_xor(acc2[k].y, o);
        }
    }

    if (g == 0) {
        float inv = 1.f / (denom + 1e-16f);
        const float* bp = &bias[l16 * 8];
        f32x4 o0, o1;
        o0.x = acc2[0].x * inv + bp[0]; o0.y = acc2[0].y * inv + bp[1];
        o0.z = acc2[1].x * inv + bp[2]; o0.w = acc2[1].y * inv + bp[3];
        o1.x = acc2[2].x * inv + bp[4]; o1.y = acc2[2].y * inv + bp[5];
        o1.z = acc2[3].x * inv + bp[6]; o1.w = acc2[3].y * inv + bp[7];
        __builtin_nontemporal_store(o0, (f32x4*)&out[(size_t)node * HC + l16 * 8]);
        __builtin_nontemporal_store(o1, (f32x4*)&out[(size_t)node * HC + l16 * 8 + 4]);
    }
}

// ---------------------------------------------------------------------------
extern "C" void kernel_launch(void* const* d_in, const int* in_sizes, int n_in,
                              void* d_out, int out_size, void* d_ws, size_t ws_size,
                              hipStream_t stream)
{
    const float* x       = (const float*)d_in[0];
    const float* W       = (const float*)d_in[1];
    const float* att_src = (const float*)d_in[2];
    const float* att_dst = (const float*)d_in[3];
    const float* bias    = (const float*)d_in[4];
    const int*   ei      = (const int*)d_in[5];
    const int E = in_sizes[5] / 2;
    const int* srcp = ei;
    const int* dstp = ei + E;
    float* out = (float*)d_out;

    char* wsb = (char*)d_ws;
    size_t off = 0;
    auto alloc = [&](size_t bytes) -> char* {
        char* p = wsb + off;
        off += (bytes + 255) & ~(size_t)255;
        return p;
    };
    unsigned short* hb = (unsigned short*)alloc((size_t)N_NODES * HC * sizeof(unsigned short)); // 25.6 MB
    float* a_src   = (float*)alloc((size_t)N_NODES * NH * sizeof(float));
    float* a_dst   = (float*)alloc((size_t)N_NODES * NH * sizeof(float));
    int*   eb      = (int*)alloc((size_t)NB * CAP * sizeof(int));          // 8.0 MB
    int*   col     = (int*)alloc((size_t)NB * CAPC * sizeof(int));         // 8.4 MB
    int2*  rowse   = (int2*)alloc((size_t)N_NODES * sizeof(int2));         // 0.8 MB
    int*   bcursor = (int*)alloc((size_t)NB * CURPAD * sizeof(int));       // 12.5 KB padded
    unsigned short* wt = (unsigned short*)alloc(128 * 128 * sizeof(unsigned short));

    const int bucketBlocks = (E + CHUNK - 1) / CHUNK;
    const int gemmBlocks   = (N_NODES + 63) / 64;

    k_pre<<<64, 256, 0, stream>>>(W, wt, bcursor);
    k_main<<<bucketBlocks + gemmBlocks, 256, 0, stream>>>(x, wt, att_src, att_dst,
                                                          hb, a_src, a_dst,
                                                          srcp, dstp, bcursor, eb, E,
                                                          bucketBlocks);
    k_csr<<<NB, 1024, 0, stream>>>(eb, bcursor, col, rowse);
    k_node<<<(N_NODES + 3) / 4, 256, 0, stream>>>(hb, a_src, a_dst, rowse, col, bias, out);
}

// Round 8
// 239.265 us; speedup vs baseline: 1.5934x; 1.0214x over previous
//
#include <hip/hip_runtime.h>
#include <hip/hip_bf16.h>
#include <math.h>

#define N_NODES 100000
#define F_IN    128
#define HC      128      // H*C
#define NH      4
#define SLOPE   0.2f

#define PADK    136      // LDS row stride in shorts (128 + 8 pad)

#define NB      196      // buckets = ceil(N/512)
#define BSH     9        // bucket = dst >> 9, local = dst & 511
#define CAP     10240    // per-bucket edge arena capacity (mean 8163, sigma ~90)
#define CAPC    10752    // per-bucket col arena (CAP + 512 self-loops)
#define CHUNK   2048     // edges per bucket block
#define CURPAD  16       // bucket_cursor stride in ints (64B: no false sharing)

typedef __attribute__((ext_vector_type(8))) short short8;   // bf16x8 MFMA frag
typedef __attribute__((ext_vector_type(4))) float f32x4;    // MFMA accum / native float4 (NT store ok)
typedef __attribute__((ext_vector_type(2))) float fx2;      // float2 for v_pk_fma_f32

static __device__ __forceinline__ float leaky(float x) { return x > 0.f ? x : SLOPE * x; }

static __device__ __forceinline__ short f2bs(float f) {
    __hip_bfloat16 b = __float2bfloat16(f);   // RTN-even
    return *reinterpret_cast<short*>(&b);
}

// unpack a bf16 pair (one u32) into a float2: lo -> .x, hi -> .y
static __device__ __forceinline__ fx2 bf2f2(unsigned int v) {
    fx2 r;
    r.x = __uint_as_float(v << 16);
    r.y = __uint_as_float(v & 0xffff0000u);
    return r;
}

// ---------------------------------------------------------------------------
// K0: one-time prep.
//  t < 16384          : W[k][n] fp32 -> wt[n][k] bf16
//  t in [16384,17408) : wa fold — wab[slot][k] = bf16( sum_c W[k][head*32+c] *
//                       att_{src|dst}[head][c] ), slot = head + 4*isdst
//  t in [17408,18432) : zero wab rows 8..15 (pad tile)
//  t < NB*CURPAD      : zero bucket cursors
// wab is the B-operand of one extra MFMA n-tile in the gemm: by linearity,
// a_src = x @ (W @ att_src) — kills the gemm's shuffle-tree epilogue.
// ---------------------------------------------------------------------------
__global__ __launch_bounds__(256) void k_pre(const float* __restrict__ W,
                                             const float* __restrict__ att_src,
                                             const float* __restrict__ att_dst,
                                             unsigned short* __restrict__ wt,
                                             unsigned short* __restrict__ wab,
                                             int* __restrict__ bucket_cursor)
{
    int t = blockIdx.x * 256 + threadIdx.x;
    if (t < 128 * 128) {
        int k = t >> 7, n = t & 127;
        wt[n * 128 + k] = (unsigned short)f2bs(W[k * HC + n]);
    } else if (t < 17408) {
        int i = t - 16384;
        int k = i >> 3, slot = i & 7;
        int head = slot & 3;
        const float* av = (slot & 4) ? att_dst : att_src;
        float dot = 0.f;
        #pragma unroll
        for (int c = 0; c < 32; ++c)
            dot += W[k * HC + head * 32 + c] * av[head * 32 + c];
        wab[slot * 128 + k] = (unsigned short)f2bs(dot);
    } else if (t < 18432) {
        int i = t - 17408;
        wab[(8 + (i >> 7)) * 128 + (i & 127)] = 0;
    }
    if (t < NB * CURPAD) bucket_cursor[t] = 0;
}

// ---------------------------------------------------------------------------
// K1 (fused): blocks [0, bucketBlocks) = edge multisplit; rest = GEMM.
// GEMM now computes a_src/a_dst via one extra MFMA n-tile (B-frag from the
// 4KB L1-resident wab) — epilogue is 8 scalar stores, no shuffle trees.
// LDS union: gemm 52.2 KB, bucket 14.3 KB -> 3 blocks/CU either way.
// ---------------------------------------------------------------------------
union SMem {
    struct {
        short xs[64 * PADK];     // bf16 x tile [row][k]   17.4 KB
        short ws[128 * PADK];    // bf16 W^T    [n][k]     34.8 KB
    } g;
    struct {
        int ebuf[CHUNK];
        unsigned char bkt[CHUNK];
        int hist[256];
        int lexcl[257];
        int gbase[256];
        int sdata[256];
    } b;
};

__global__ __launch_bounds__(256) void k_main(const float* __restrict__ x,
                                              const unsigned short* __restrict__ wt,
                                              const unsigned short* __restrict__ wab,
                                              unsigned short* __restrict__ hb,
                                              float* __restrict__ a_src,
                                              float* __restrict__ a_dst,
                                              const int* __restrict__ srcp,
                                              const int* __restrict__ dstp,
                                              int* __restrict__ bucket_cursor,
                                              int* __restrict__ eb, int E,
                                              int bucketBlocks)
{
    __shared__ SMem sm;
    const int t = threadIdx.x;

    if ((int)blockIdx.x < bucketBlocks) {
        // ---------------------------- multisplit --------------------------
        const int base = blockIdx.x * CHUNK;

        sm.b.hist[t] = 0;
        __syncthreads();

        int sreg[8], dreg[8];
        #pragma unroll
        for (int j = 0; j < CHUNK / 256; ++j) {
            int i = base + t + j * 256;
            bool v = i < E;
            sreg[j] = v ? srcp[i] : 0;
            dreg[j] = v ? dstp[i] : -1;
            if (v) atomicAdd(&sm.b.hist[dreg[j] >> BSH], 1);
        }
        __syncthreads();

        int cnt = sm.b.hist[t];
        sm.b.sdata[t] = cnt;
        __syncthreads();
        for (int o = 1; o < 256; o <<= 1) {
            int add = (t >= o) ? sm.b.sdata[t - o] : 0;
            __syncthreads();
            sm.b.sdata[t] += add;
            __syncthreads();
        }
        int excl = sm.b.sdata[t] - cnt;
        sm.b.lexcl[t] = excl;
        if (t == 255) sm.b.lexcl[256] = sm.b.sdata[255];
        sm.b.hist[t] = excl;
        int gb = 0;
        if (t < NB && cnt > 0) gb = atomicAdd(&bucket_cursor[t * CURPAD], cnt);
        sm.b.gbase[t] = t * CAP + gb;
        __syncthreads();

        #pragma unroll
        for (int j = 0; j < CHUNK / 256; ++j) {
            if (dreg[j] >= 0) {
                int b = dreg[j] >> BSH;
                int r = atomicAdd(&sm.b.hist[b], 1);
                sm.b.ebuf[r] = (sreg[j] << BSH) | (dreg[j] & 511);
                sm.b.bkt[r] = (unsigned char)b;
            }
        }
        __syncthreads();

        const int blockTotal = sm.b.lexcl[256];
        for (int i = t; i < blockTotal; i += 256) {
            int b = sm.b.bkt[i];
            eb[sm.b.gbase[b] + (i - sm.b.lexcl[b])] = sm.b.ebuf[i];
        }
    } else {
        // ------------------------------ GEMM ------------------------------
        const int r0 = (blockIdx.x - bucketBlocks) * 64;

        for (int i = t; i < 2048; i += 256) {
            int row = i >> 5, kq = (i & 31) * 4;
            int gr = r0 + row;
            float4 v = make_float4(0.f, 0.f, 0.f, 0.f);
            if (gr < N_NODES) v = ((const float4*)(x + (size_t)gr * F_IN))[i & 31];
            short* p = &sm.g.xs[row * PADK + kq];
            p[0] = f2bs(v.x); p[1] = f2bs(v.y); p[2] = f2bs(v.z); p[3] = f2bs(v.w);
        }
        for (int i = t; i < 2048; i += 256) {
            int n = i >> 4, k0 = (i & 15) * 8;
            *(float4*)&sm.g.ws[n * PADK + k0] = *(const float4*)&wt[n * 128 + k0];
        }
        __syncthreads();

        const int wave = t >> 6, lane = t & 63;
        const int quad = lane >> 4, l16 = lane & 15;
        const int wrow = wave * 16;

        f32x4 acc[8];
        #pragma unroll
        for (int nt = 0; nt < 8; ++nt) acc[nt] = (f32x4){0.f, 0.f, 0.f, 0.f};
        f32x4 acca = (f32x4){0.f, 0.f, 0.f, 0.f};   // a_src/a_dst tile

        const short* ap = &sm.g.xs[(wrow + l16) * PADK + quad * 8];
        #pragma unroll
        for (int kb = 0; kb < 4; ++kb) {
            short8 a = *(const short8*)(ap + kb * 32);
            #pragma unroll
            for (int nt = 0; nt < 8; ++nt) {
                short8 b = *(const short8*)&sm.g.ws[(nt * 16 + l16) * PADK + kb * 32 + quad * 8];
                acc[nt] = __builtin_amdgcn_mfma_f32_16x16x32_bf16(a, b, acc[nt], 0, 0, 0);
            }
            short8 bwa = *(const short8*)&wab[l16 * 128 + kb * 32 + quad * 8];
            acca = __builtin_amdgcn_mfma_f32_16x16x32_bf16(a, bwa, acca, 0, 0, 0);
        }

        #pragma unroll
        for (int g = 0; g < 4; ++g) {
            int r = r0 + wrow + quad * 4 + g;
            if (r < N_NODES) {
                #pragma unroll
                for (int nt = 0; nt < 8; ++nt)
                    hb[(size_t)r * HC + nt * 16 + l16] = (unsigned short)f2bs(acc[nt][g]);
                // a-tile: col l16<4 = a_src heads, 4..7 = a_dst heads
                if (l16 < 4)      a_src[r * NH + l16]       = acca[g];
                else if (l16 < 8) a_dst[r * NH + (l16 - 4)] = acca[g];
            }
        }
    }
}

// ---------------------------------------------------------------------------
// K2: per-bucket CSR build, 1024 threads/block. col staged in LDS, tail
// zero-filled only to top+32 (k_node's max prefetch reach), PACKED flush
// (round-7's full-CAPC flush cost +16MB FETCH in k_node = +5 µs).
// Self-loop at slot 0 of each node.
// ---------------------------------------------------------------------------
__global__ __launch_bounds__(1024) void k_csr(const int* __restrict__ eb,
                                              const int* __restrict__ bucket_cursor,
                                              int* __restrict__ col,
                                              int2* __restrict__ rowse)
{
    __shared__ int deg[512];
    __shared__ int sdata[256];
    __shared__ alignas(16) int colL[CAPC];   // 43 KB

    const int t  = threadIdx.x;
    const int b  = blockIdx.x;
    const int n0 = b * 512;
    const int cnt   = bucket_cursor[b * CURPAD];
    const int ebase = b * CAP;
    const int gofs  = b * CAPC;
    const int nvalid = min(512, N_NODES - n0);
    const int top = cnt + nvalid;            // used entries in this arena
    const int upper = min(CAPC, (top + 32 + 15) & ~15);  // flush bound

    if (t < 512) deg[t] = (t < nvalid) ? 1 : 0;
    __syncthreads();

    for (int i = t; i < cnt; i += 1024)
        atomicAdd(&deg[eb[ebase + i] & 511], 1);
    __syncthreads();

    int d0 = 0, d1 = 0, ps = 0;
    if (t < 256) {
        d0 = deg[2 * t]; d1 = deg[2 * t + 1];
        ps = d0 + d1;
        sdata[t] = ps;
    }
    __syncthreads();
    for (int o = 1; o < 256; o <<= 1) {
        int add = 0;
        if (t < 256 && t >= o) add = sdata[t - o];
        __syncthreads();
        if (t < 256) sdata[t] += add;
        __syncthreads();
    }
    if (t < 256) {
        int e0 = sdata[t] - ps;
        int e1 = e0 + d0;
        int na = n0 + 2 * t, nb2 = n0 + 2 * t + 1;
        if (na < N_NODES) {
            rowse[na] = make_int2(gofs + e0, gofs + e0 + d0);
            colL[e0] = na;
        }
        if (nb2 < N_NODES) {
            rowse[nb2] = make_int2(gofs + e1, gofs + e1 + d1);
            colL[e1] = nb2;
        }
        deg[2 * t]     = e0 + 1;
        deg[2 * t + 1] = e1 + 1;
    }
    __syncthreads();

    for (int i = t; i < cnt; i += 1024) {
        int v = eb[ebase + i];
        int r = atomicAdd(&deg[v & 511], 1);
        colL[r] = v >> BSH;
    }
    // zero the prefetch tail so k_node can read past the end safely
    for (int i = top + t; i < upper; i += 1024) colL[i] = 0;
    __syncthreads();

    // packed coalesced flush: 16B per lane, only the used region
    const int4* s4 = (const int4*)colL;
    int4* d4 = (int4*)(col + gofs);
    const int n4 = upper >> 2;
    for (int i = t; i < n4; i += 1024) d4[i] = s4[i];
}

// ---------------------------------------------------------------------------
// K3: per-dst-node softmax + aggregation. 16-lane groups own edges; 3-deep
// GUARD-FREE software pipeline (col tail zero-filled); packed float2 FMAs.
// ---------------------------------------------------------------------------
__global__ __launch_bounds__(256) void k_node(const unsigned short* __restrict__ hb,
                                              const float* __restrict__ a_src,
                                              const float* __restrict__ a_dst,
                                              const int2* __restrict__ rowse,
                                              const int* __restrict__ col,
                                              const float* __restrict__ bias,
                                              float* __restrict__ out)
{
    const int lane = threadIdx.x & 63;
    const int node = blockIdx.x * 4 + (threadIdx.x >> 6);
    if (node >= N_NODES) return;

    const int g   = lane >> 4;   // edge slot within wave
    const int l16 = lane & 15;   // 16B slice within 256B row
    const int myh = l16 >> 2;    // head of my 8 elements

    const int2 se = rowse[node];
    const int r0 = se.x;
    const int cnt = se.y - se.x;

    const float adm = a_dst[node * NH + myh];

    fx2 acc2[4];
    #pragma unroll
    for (int k = 0; k < 4; ++k) acc2[k] = (fx2){0.f, 0.f};
    float denom = 0.f;

    // pipeline prologue (all loads unconditionally safe within the arena)
    int   cA0 = col[r0 + g];
    int   cA1 = col[r0 + 4 + g];
    float aA0 = a_src[cA0 * NH + myh];
    float aA1 = a_src[cA1 * NH + myh];
    uint4 hA0 = ((const uint4*)(hb + (size_t)cA0 * HC))[l16];
    uint4 hA1 = ((const uint4*)(hb + (size_t)cA1 * HC))[l16];
    int   cB0 = col[r0 + 8 + g];
    int   cB1 = col[r0 + 12 + g];

    for (int i = 0; i < cnt; i += 8) {
        // gathers for iter i+8 (indices from zero-tail are node 0 -> valid)
        float aN0 = a_src[cB0 * NH + myh];
        float aN1 = a_src[cB1 * NH + myh];
        uint4 hN0 = ((const uint4*)(hb + (size_t)cB0 * HC))[l16];
        uint4 hN1 = ((const uint4*)(hb + (size_t)cB1 * HC))[l16];
        // cols for iter i+16 (max index top+23 < flush bound: safe)
        int cC0 = col[r0 + i + 16 + g];
        int cC1 = col[r0 + i + 20 + g];

        // compute iter i: only p is masked
        float p0 = (i + g     < cnt) ? __expf(leaky(aA0 + adm)) : 0.f;
        float p1 = (i + 4 + g < cnt) ? __expf(leaky(aA1 + adm)) : 0.f;
        denom += p0 + p1;
        fx2 pb0 = (fx2){p0, p0}, pb1 = (fx2){p1, p1};
        acc2[0] = __builtin_elementwise_fma(bf2f2(hA0.x), pb0, acc2[0]);
        acc2[0] = __builtin_elementwise_fma(bf2f2(hA1.x), pb1, acc2[0]);
        acc2[1] = __builtin_elementwise_fma(bf2f2(hA0.y), pb0, acc2[1]);
        acc2[1] = __builtin_elementwise_fma(bf2f2(hA1.y), pb1, acc2[1]);
        acc2[2] = __builtin_elementwise_fma(bf2f2(hA0.z), pb0, acc2[2]);
        acc2[2] = __builtin_elementwise_fma(bf2f2(hA1.z), pb1, acc2[2]);
        acc2[3] = __builtin_elementwise_fma(bf2f2(hA0.w), pb0, acc2[3]);
        acc2[3] = __builtin_elementwise_fma(bf2f2(hA1.w), pb1, acc2[3]);

        // rotate pipeline
        aA0 = aN0; aA1 = aN1; hA0 = hN0; hA1 = hN1;
        cB0 = cC0; cB1 = cC1;
    }

    // reduce the 4 edge-groups: lanes l, l^16, l^32, l^48 hold the same slice
    #pragma unroll
    for (int o = 16; o < 64; o <<= 1) {
        denom += __shfl_xor(denom, o);
        #pragma unroll
        for (int k = 0; k < 4; ++k) {
            acc2[k].x += __shfl_xor(acc2[k].x, o);
            acc2[k].y += __shfl_xor(acc2[k].y, o);
        }
    }

    if (g == 0) {
        float inv = 1.f / (denom + 1e-16f);
        const float* bp = &bias[l16 * 8];
        f32x4 o0, o1;
        o0.x = acc2[0].x * inv + bp[0]; o0.y = acc2[0].y * inv + bp[1];
        o0.z = acc2[1].x * inv + bp[2]; o0.w = acc2[1].y * inv + bp[3];
        o1.x = acc2[2].x * inv + bp[4]; o1.y = acc2[2].y * inv + bp[5];
        o1.z = acc2[3].x * inv + bp[6]; o1.w = acc2[3].y * inv + bp[7];
        __builtin_nontemporal_store(o0, (f32x4*)&out[(size_t)node * HC + l16 * 8]);
        __builtin_nontemporal_store(o1, (f32x4*)&out[(size_t)node * HC + l16 * 8 + 4]);
    }
}

// ---------------------------------------------------------------------------
extern "C" void kernel_launch(void* const* d_in, const int* in_sizes, int n_in,
                              void* d_out, int out_size, void* d_ws, size_t ws_size,
                              hipStream_t stream)
{
    const float* x       = (const float*)d_in[0];
    const float* W       = (const float*)d_in[1];
    const float* att_src = (const float*)d_in[2];
    const float* att_dst = (const float*)d_in[3];
    const float* bias    = (const float*)d_in[4];
    const int*   ei      = (const int*)d_in[5];
    const int E = in_sizes[5] / 2;
    const int* srcp = ei;
    const int* dstp = ei + E;
    float* out = (float*)d_out;

    char* wsb = (char*)d_ws;
    size_t off = 0;
    auto alloc = [&](size_t bytes) -> char* {
        char* p = wsb + off;
        off += (bytes + 255) & ~(size_t)255;
        return p;
    };
    unsigned short* hb = (unsigned short*)alloc((size_t)N_NODES * HC * sizeof(unsigned short)); // 25.6 MB
    float* a_src   = (float*)alloc((size_t)N_NODES * NH * sizeof(float));
    float* a_dst   = (float*)alloc((size_t)N_NODES * NH * sizeof(float));
    int*   eb      = (int*)alloc((size_t)NB * CAP * sizeof(int));          // 8.0 MB
    int*   col     = (int*)alloc((size_t)NB * CAPC * sizeof(int));         // 8.4 MB
    int2*  rowse   = (int2*)alloc((size_t)N_NODES * sizeof(int2));         // 0.8 MB
    int*   bcursor = (int*)alloc((size_t)NB * CURPAD * sizeof(int));       // 12.5 KB padded
    unsigned short* wt  = (unsigned short*)alloc(128 * 128 * sizeof(unsigned short));
    unsigned short* wab = (unsigned short*)alloc(16 * 128 * sizeof(unsigned short)); // 4 KB

    const int bucketBlocks = (E + CHUNK - 1) / CHUNK;
    const int gemmBlocks   = (N_NODES + 63) / 64;

    k_pre<<<73, 256, 0, stream>>>(W, att_src, att_dst, wt, wab, bcursor);
    k_main<<<bucketBlocks + gemmBlocks, 256, 0, stream>>>(x, wt, wab,
                                                          hb, a_src, a_dst,
                                                          srcp, dstp, bcursor, eb, E,
                                                          bucketBlocks);
    k_csr<<<NB, 1024, 0, stream>>>(eb, bcursor, col, rowse);
    k_node<<<(N_NODES + 3) / 4, 256, 0, stream>>>(hb, a_src, a_dst, rowse, col, bias, out);
}